// Round 1
// baseline (6245.055 us; speedup 1.0000x reference)
//
#include <hip/hip_runtime.h>

// NextBasketEncoder — round 1: correct fp32 pipeline, rows-in-lanes layouts,
// float4 weight reads, transposed weights staged in ws.
// B=1024, O=50, L=20, D=64, H=128, DM=256, FF=512, V=49688.

#define B_ 1024
#define O_ 50

__device__ __forceinline__ float sig_(float x)  { return 1.0f / (1.0f + __expf(-x)); }
__device__ __forceinline__ float tanh_(float x) { return 2.0f / (1.0f + __expf(-2.0f * x)) - 1.0f; }

// ---------------- generic transpose: src[R][C] -> dst[C][R] ----------------
__global__ void k_transpose(const float* __restrict__ src, float* __restrict__ dst, int R, int C) {
  int i = blockIdx.x * 256 + threadIdx.x;
  if (i < R * C) {
    int r = i / C, c = i - r * C;
    dst[c * R + r] = src[i];
  }
}

// ---------------- stage 1: gather + item MHA (nh=4, hd=16) + mean + proj ----
// one block per (b,o); 320 threads (5 waves). Writes X[O][B][64].
__global__ __launch_bounds__(320) void k_item_attn(
    const int* __restrict__ oh, const float* __restrict__ emb,
    const float* __restrict__ wqkvT /*[64][192]*/, const float* __restrict__ bqkv,
    const float* __restrict__ woT /*[64][64]*/, const float* __restrict__ bob,
    float* __restrict__ X)
{
  __shared__ __align__(16) float Es[20][68];
  __shared__ __align__(16) float QK[20][196];   // cols 0-63 q, 64-127 k, 128-191 v
  __shared__ float P[4][20][25];
  __shared__ __align__(16) float ATT[20][68];
  __shared__ float MEANATT[64];

  int bo = blockIdx.x;
  int b = bo / 50, o = bo - b * 50;
  int t = threadIdx.x;

  // gather 20x64 embedding rows
  for (int e = t; e < 1280; e += 320) {
    int l = e >> 6, d = e & 63;
    Es[l][d] = emb[(size_t)oh[bo * 20 + l] * 64 + d];
  }
  __syncthreads();

  // qkv: row-in-lane (r = t>>4 covers 20 rows), 12 cols per thread
  {
    int r = t >> 4, cg = t & 15, c0 = cg * 12;
    float acc[12];
#pragma unroll
    for (int j = 0; j < 12; ++j) acc[j] = bqkv[c0 + j];
#define IA_QKV_K(S, KIDX) { \
      const float* wp_ = &wqkvT[(KIDX) * 192 + c0]; \
      float4 w0_ = *(const float4*)wp_; \
      float4 w1_ = *(const float4*)(wp_ + 4); \
      float4 w2_ = *(const float4*)(wp_ + 8); \
      acc[0] += (S)*w0_.x; acc[1] += (S)*w0_.y; acc[2] += (S)*w0_.z; acc[3] += (S)*w0_.w; \
      acc[4] += (S)*w1_.x; acc[5] += (S)*w1_.y; acc[6] += (S)*w1_.z; acc[7] += (S)*w1_.w; \
      acc[8] += (S)*w2_.x; acc[9] += (S)*w2_.y; acc[10] += (S)*w2_.z; acc[11] += (S)*w2_.w; }
    for (int k4 = 0; k4 < 64; k4 += 4) {
      float4 ev = *(const float4*)&Es[r][k4];
      IA_QKV_K(ev.x, k4 + 0)
      IA_QKV_K(ev.y, k4 + 1)
      IA_QKV_K(ev.z, k4 + 2)
      IA_QKV_K(ev.w, k4 + 3)
    }
#pragma unroll
    for (int j = 0; j < 12; ++j) QK[r][c0 + j] = acc[j];
  }
  __syncthreads();

  // scores: 4 heads x 20 x 20, hd=16, scale 0.25
  for (int e = t; e < 1600; e += 320) {
    int h = e / 400, rem = e - h * 400;
    int i = rem / 20, j = rem - i * 20;
    const float* qp = &QK[i][h * 16];
    const float* kp = &QK[j][64 + h * 16];
    float acc = 0.f;
#pragma unroll
    for (int k4 = 0; k4 < 16; k4 += 4) {
      float4 qv = *(const float4*)(qp + k4);
      float4 kv = *(const float4*)(kp + k4);
      acc += qv.x * kv.x + qv.y * kv.y + qv.z * kv.z + qv.w * kv.w;
    }
    P[h][i][j] = acc * 0.25f;
  }
  __syncthreads();

  // softmax over j (80 rows)
  if (t < 80) {
    int h = t / 20, i = t - h * 20;
    float m = -1e30f;
    for (int j = 0; j < 20; ++j) m = fmaxf(m, P[h][i][j]);
    float s = 0.f;
    for (int j = 0; j < 20; ++j) { float v = __expf(P[h][i][j] - m); P[h][i][j] = v; s += v; }
    float inv = 1.f / s;
    for (int j = 0; j < 20; ++j) P[h][i][j] *= inv;
  }
  __syncthreads();

  // AV: one float4 of cols per thread (320 = 20 rows x 16 quad-groups)
  {
    int i = t >> 4, c0 = (t & 15) * 4, h = c0 >> 4;
    float4 acc = make_float4(0.f, 0.f, 0.f, 0.f);
    for (int j = 0; j < 20; ++j) {
      float p = P[h][i][j];
      float4 v = *(const float4*)&QK[j][128 + c0];
      acc.x += p * v.x; acc.y += p * v.y; acc.z += p * v.z; acc.w += p * v.w;
    }
    *(float4*)&ATT[i][c0] = acc;
  }
  __syncthreads();

  // mean over L commutes with out-proj: project the mean (20x cheaper)
  if (t < 64) {
    float a = 0.f;
    for (int i = 0; i < 20; ++i) a += ATT[i][t];
    MEANATT[t] = a * 0.05f;
  }
  __syncthreads();
  if (t < 64) {
    float acc = bob[t];
    for (int k = 0; k < 64; ++k) acc += MEANATT[k] * woT[k * 64 + t];
    X[(size_t)(o * B_ + b) * 64 + t] = acc;
  }
}

// ---------------- stage 2: bidirectional GRU ----------------
// 256 blocks: blocks 0-127 fwd, 128-255 bwd; each owns 8 batch rows, loops 50 steps.
// thread = (r = t&7 rows-in-lanes, hg = t>>3 -> 4 hidden cols), gates local (no LDS roundtrip).
__global__ __launch_bounds__(256) void k_gru(
    const float* __restrict__ X /*[O][B][64]*/,
    const float* __restrict__ wiT_f /*[64][384]*/, const float* __restrict__ whT_f /*[128][384]*/,
    const float* __restrict__ bi_f, const float* __restrict__ bh_f,
    const float* __restrict__ wiT_b, const float* __restrict__ whT_b,
    const float* __restrict__ bi_b, const float* __restrict__ bh_b,
    float* __restrict__ G /*[B][O][256]*/)
{
  __shared__ __align__(16) float hs[8][132];
  __shared__ __align__(16) float xs[8][68];
  int dir = blockIdx.x >> 7;
  int rb = (blockIdx.x & 127) * 8;
  const float* wiT = dir ? wiT_b : wiT_f;
  const float* whT = dir ? whT_b : whT_f;
  const float* bi  = dir ? bi_b : bi_f;
  const float* bh  = dir ? bh_b : bh_f;
  int t = threadIdx.x;
  int r = t & 7, hc = (t >> 3) * 4;

  for (int e = t; e < 1024; e += 256) hs[e >> 7][e & 127] = 0.f;
  __syncthreads();

  for (int s = 0; s < 50; ++s) {
    int o = dir ? 49 - s : s;
    for (int e = t; e < 512; e += 256) {
      int rr = e >> 6, d = e & 63;
      xs[rr][d] = X[(size_t)(o * B_ + rb + rr) * 64 + d];
    }
    __syncthreads();

    float ai[12], ah[12];
#pragma unroll
    for (int sec = 0; sec < 3; ++sec) {
      float4 b4 = *(const float4*)&bi[sec * 128 + hc];
      ai[sec*4+0] = b4.x; ai[sec*4+1] = b4.y; ai[sec*4+2] = b4.z; ai[sec*4+3] = b4.w;
      float4 h4 = *(const float4*)&bh[sec * 128 + hc];
      ah[sec*4+0] = h4.x; ah[sec*4+1] = h4.y; ah[sec*4+2] = h4.z; ah[sec*4+3] = h4.w;
    }
#define GRU_K(S, WP, A) { \
      const float* wp_ = (WP); \
      float4 w0_ = *(const float4*)&wp_[hc]; \
      float4 w1_ = *(const float4*)&wp_[128 + hc]; \
      float4 w2_ = *(const float4*)&wp_[256 + hc]; \
      A[0] += (S)*w0_.x; A[1] += (S)*w0_.y; A[2] += (S)*w0_.z; A[3] += (S)*w0_.w; \
      A[4] += (S)*w1_.x; A[5] += (S)*w1_.y; A[6] += (S)*w1_.z; A[7] += (S)*w1_.w; \
      A[8] += (S)*w2_.x; A[9] += (S)*w2_.y; A[10] += (S)*w2_.z; A[11] += (S)*w2_.w; }
    for (int k4 = 0; k4 < 64; k4 += 4) {
      float4 xv = *(const float4*)&xs[r][k4];
      GRU_K(xv.x, wiT + (k4+0)*384, ai)
      GRU_K(xv.y, wiT + (k4+1)*384, ai)
      GRU_K(xv.z, wiT + (k4+2)*384, ai)
      GRU_K(xv.w, wiT + (k4+3)*384, ai)
    }
    for (int k4 = 0; k4 < 128; k4 += 4) {
      float4 hv = *(const float4*)&hs[r][k4];
      GRU_K(hv.x, whT + (k4+0)*384, ah)
      GRU_K(hv.y, whT + (k4+1)*384, ah)
      GRU_K(hv.z, whT + (k4+2)*384, ah)
      GRU_K(hv.w, whT + (k4+3)*384, ah)
    }
    float hn[4];
#pragma unroll
    for (int j = 0; j < 4; ++j) {
      float rr_ = sig_(ai[j] + ah[j]);
      float zz  = sig_(ai[4+j] + ah[4+j]);
      float nn  = tanh_(ai[8+j] + rr_ * ah[8+j]);
      hn[j] = (1.f - zz) * nn + zz * hs[r][hc + j];
    }
    __syncthreads();   // all reads of hs done
#pragma unroll
    for (int j = 0; j < 4; ++j) hs[r][hc + j] = hn[j];
    *(float4*)&G[((size_t)(rb + r) * 50 + o) * 256 + dir * 128 + hc] =
        make_float4(hn[0], hn[1], hn[2], hn[3]);
    __syncthreads();
  }
}

// ---------------- stage 3a: transformer attention (per b, per head) ----------
// 4096 blocks x 384 threads. Computes this head's q/k/v (dot-256 from G),
// softmax, AV; writes pre-out-proj ATT[B][O][256] head slice.
__global__ __launch_bounds__(384) void k_t_attn(
    const float* __restrict__ G, const float* __restrict__ wqkvT /*[256][768]*/,
    const float* __restrict__ bqkv, float* __restrict__ ATT)
{
  __shared__ __align__(16) float gs[25][260];
  __shared__ __align__(16) float qs[50][68], ks[50][68], vs[50][68];
  __shared__ float P[50][52];
  int b = blockIdx.x >> 2, h = blockIdx.x & 3;
  int t = threadIdx.x;
  int r = t & 31, cg = t >> 5;          // cg 0..11
  int c0 = cg * 16;                     // within [0,192)
  int sec = c0 >> 6;                    // 0=q 1=k 2=v
  int col0 = sec * 256 + h * 64 + (c0 & 63);
  const float* gb = G + (size_t)b * 50 * 256;

  for (int ch = 0; ch < 2; ++ch) {
    for (int e = t; e < 6400; e += 384) gs[e >> 8][e & 255] = gb[ch * 6400 + e];
    __syncthreads();
    if (r < 25) {
      float acc[16];
#pragma unroll
      for (int j = 0; j < 16; ++j) acc[j] = bqkv[col0 + j];
      for (int k4 = 0; k4 < 256; k4 += 4) {
        float4 gv = *(const float4*)&gs[r][k4];
#define TA_QKV_K(S, KIDX) { \
        const float* wp_ = &wqkvT[(size_t)(KIDX) * 768 + col0]; \
        float4 w0_ = *(const float4*)wp_; \
        float4 w1_ = *(const float4*)(wp_ + 4); \
        float4 w2_ = *(const float4*)(wp_ + 8); \
        float4 w3_ = *(const float4*)(wp_ + 12); \
        acc[0] += (S)*w0_.x; acc[1] += (S)*w0_.y; acc[2] += (S)*w0_.z; acc[3] += (S)*w0_.w; \
        acc[4] += (S)*w1_.x; acc[5] += (S)*w1_.y; acc[6] += (S)*w1_.z; acc[7] += (S)*w1_.w; \
        acc[8] += (S)*w2_.x; acc[9] += (S)*w2_.y; acc[10] += (S)*w2_.z; acc[11] += (S)*w2_.w; \
        acc[12] += (S)*w3_.x; acc[13] += (S)*w3_.y; acc[14] += (S)*w3_.z; acc[15] += (S)*w3_.w; }
        TA_QKV_K(gv.x, k4 + 0)
        TA_QKV_K(gv.y, k4 + 1)
        TA_QKV_K(gv.z, k4 + 2)
        TA_QKV_K(gv.w, k4 + 3)
      }
      int row = ch * 25 + r;
      float* dst = (sec == 0) ? &qs[row][0] : (sec == 1) ? &ks[row][0] : &vs[row][0];
      int cc = c0 & 63;
#pragma unroll
      for (int j = 0; j < 16; j += 4)
        *(float4*)&dst[cc + j] = make_float4(acc[j], acc[j+1], acc[j+2], acc[j+3]);
    }
    __syncthreads();
  }

  // scores 50x50, hd=64, scale 0.125
  for (int e = t; e < 2500; e += 384) {
    int i = e / 50, j = e - i * 50;
    float acc = 0.f;
#pragma unroll
    for (int k4 = 0; k4 < 64; k4 += 4) {
      float4 qv = *(const float4*)&qs[i][k4];
      float4 kv = *(const float4*)&ks[j][k4];
      acc += qv.x * kv.x + qv.y * kv.y + qv.z * kv.z + qv.w * kv.w;
    }
    P[i][j] = acc * 0.125f;
  }
  __syncthreads();
  if (t < 50) {
    float m = -1e30f;
    for (int j = 0; j < 50; ++j) m = fmaxf(m, P[t][j]);
    float s = 0.f;
    for (int j = 0; j < 50; ++j) { float v = __expf(P[t][j] - m); P[t][j] = v; s += v; }
    float inv = 1.f / s;
    for (int j = 0; j < 50; ++j) P[t][j] *= inv;
  }
  __syncthreads();
  // AV: 50 rows x 16 col-quads
  for (int e = t; e < 800; e += 384) {
    int i = e >> 4, cq = (e & 15) * 4;
    float4 acc = make_float4(0.f, 0.f, 0.f, 0.f);
    for (int j = 0; j < 50; ++j) {
      float p = P[i][j];
      float4 v = *(const float4*)&vs[j][cq];
      acc.x += p * v.x; acc.y += p * v.y; acc.z += p * v.z; acc.w += p * v.w;
    }
    *(float4*)&ATT[((size_t)b * 50 + i) * 256 + h * 64 + cq] = acc;
  }
}

// ---------------- stage 3b: out-proj + residual + LN1 (in place on ATT) -----
// 3200 blocks x 256 threads; 16 rows/block; thread = (r = t&15, 16 cols).
__global__ __launch_bounds__(256) void k_t_out_ln(
    const float* __restrict__ G, float* __restrict__ ATT,
    const float* __restrict__ woT /*[256][256]*/, const float* __restrict__ bo2,
    const float* __restrict__ lng, const float* __restrict__ lnb)
{
  __shared__ __align__(16) float a[16][260];
  __shared__ float rsum[16][17], rsq[16][17], stat[16][2];
  int row0 = blockIdx.x * 16;
  int t = threadIdx.x;
  for (int e = t; e < 4096; e += 256) a[e >> 8][e & 255] = ATT[(size_t)row0 * 256 + e];
  __syncthreads();
  int r = t & 15, cg = t >> 4, c0 = cg * 16;
  float acc[16];
#pragma unroll
  for (int j = 0; j < 16; j += 4) {
    float4 bv = *(const float4*)&bo2[c0 + j];
    acc[j] = bv.x; acc[j+1] = bv.y; acc[j+2] = bv.z; acc[j+3] = bv.w;
  }
  for (int k = 0; k < 256; ++k) {
    float av = a[r][k];
#pragma unroll
    for (int j = 0; j < 16; j += 4) {
      float4 w = *(const float4*)&woT[(size_t)k * 256 + c0 + j];
      acc[j] += av * w.x; acc[j+1] += av * w.y; acc[j+2] += av * w.z; acc[j+3] += av * w.w;
    }
  }
  const float* grow = &G[(size_t)(row0 + r) * 256 + c0];
#pragma unroll
  for (int j = 0; j < 16; j += 4) {
    float4 gv = *(const float4*)(grow + j);
    acc[j] += gv.x; acc[j+1] += gv.y; acc[j+2] += gv.z; acc[j+3] += gv.w;
  }
  float ps = 0.f, pq = 0.f;
#pragma unroll
  for (int j = 0; j < 16; ++j) { ps += acc[j]; pq += acc[j] * acc[j]; }
  rsum[r][cg] = ps; rsq[r][cg] = pq;
  __syncthreads();
  if (t < 16) {
    float s = 0.f, sq = 0.f;
    for (int c = 0; c < 16; ++c) { s += rsum[t][c]; sq += rsq[t][c]; }
    float m = s * (1.f / 256.f);
    float v = sq * (1.f / 256.f) - m * m;
    stat[t][0] = m; stat[t][1] = rsqrtf(v + 1e-5f);
  }
  __syncthreads();
  float m = stat[r][0], rs = stat[r][1];
  float* orow = &ATT[(size_t)(row0 + r) * 256 + c0];
#pragma unroll
  for (int j = 0; j < 16; j += 4) {
    float4 gv = *(const float4*)&lng[c0 + j];
    float4 bv = *(const float4*)&lnb[c0 + j];
    float4 ov;
    ov.x = (acc[j]   - m) * rs * gv.x + bv.x;
    ov.y = (acc[j+1] - m) * rs * gv.y + bv.y;
    ov.z = (acc[j+2] - m) * rs * gv.z + bv.z;
    ov.w = (acc[j+3] - m) * rs * gv.w + bv.w;
    *(float4*)(orow + j) = ov;
  }
}

// ---------------- stage 3c: FFN + residual + LN2 -> H2 ----------------------
__global__ __launch_bounds__(256) void k_t_ffn(
    const float* __restrict__ H1, float* __restrict__ H2,
    const float* __restrict__ w1T /*[256][512]*/, const float* __restrict__ b1,
    const float* __restrict__ w2T /*[512][256]*/, const float* __restrict__ b2,
    const float* __restrict__ lng, const float* __restrict__ lnb)
{
  __shared__ __align__(16) float h1s[16][260];
  __shared__ __align__(16) float f1[16][516];
  __shared__ float rsum[16][17], rsq[16][17], stat[16][2];
  int row0 = blockIdx.x * 16;
  int t = threadIdx.x;
  for (int e = t; e < 4096; e += 256) h1s[e >> 8][e & 255] = H1[(size_t)row0 * 256 + e];
  __syncthreads();
  int r = t & 15, cg = t >> 4;
  {
    int c0 = cg * 32;
    float acc[32];
#pragma unroll
    for (int j = 0; j < 32; j += 4) {
      float4 bv = *(const float4*)&b1[c0 + j];
      acc[j] = bv.x; acc[j+1] = bv.y; acc[j+2] = bv.z; acc[j+3] = bv.w;
    }
    for (int k = 0; k < 256; ++k) {
      float hv = h1s[r][k];
#pragma unroll
      for (int j = 0; j < 32; j += 4) {
        float4 w = *(const float4*)&w1T[(size_t)k * 512 + c0 + j];
        acc[j] += hv * w.x; acc[j+1] += hv * w.y; acc[j+2] += hv * w.z; acc[j+3] += hv * w.w;
      }
    }
#pragma unroll
    for (int j = 0; j < 32; j += 4) {
      float4 ov;
      ov.x = fmaxf(acc[j],   0.f); ov.y = fmaxf(acc[j+1], 0.f);
      ov.z = fmaxf(acc[j+2], 0.f); ov.w = fmaxf(acc[j+3], 0.f);
      *(float4*)&f1[r][c0 + j] = ov;
    }
  }
  __syncthreads();
  int c0 = cg * 16;
  float acc[16];
#pragma unroll
  for (int j = 0; j < 16; j += 4) {
    float4 bv = *(const float4*)&b2[c0 + j];
    acc[j] = bv.x; acc[j+1] = bv.y; acc[j+2] = bv.z; acc[j+3] = bv.w;
  }
  for (int k = 0; k < 512; ++k) {
    float fv = f1[r][k];
#pragma unroll
    for (int j = 0; j < 16; j += 4) {
      float4 w = *(const float4*)&w2T[(size_t)k * 256 + c0 + j];
      acc[j] += fv * w.x; acc[j+1] += fv * w.y; acc[j+2] += fv * w.z; acc[j+3] += fv * w.w;
    }
  }
#pragma unroll
  for (int j = 0; j < 16; ++j) acc[j] += h1s[r][c0 + j];
  float ps = 0.f, pq = 0.f;
#pragma unroll
  for (int j = 0; j < 16; ++j) { ps += acc[j]; pq += acc[j] * acc[j]; }
  rsum[r][cg] = ps; rsq[r][cg] = pq;
  __syncthreads();
  if (t < 16) {
    float s = 0.f, sq = 0.f;
    for (int c = 0; c < 16; ++c) { s += rsum[t][c]; sq += rsq[t][c]; }
    float m = s * (1.f / 256.f);
    float v = sq * (1.f / 256.f) - m * m;
    stat[t][0] = m; stat[t][1] = rsqrtf(v + 1e-5f);
  }
  __syncthreads();
  float m = stat[r][0], rs = stat[r][1];
  float* orow = &H2[(size_t)(row0 + r) * 256 + c0];
#pragma unroll
  for (int j = 0; j < 16; j += 4) {
    float4 gv = *(const float4*)&lng[c0 + j];
    float4 bv = *(const float4*)&lnb[c0 + j];
    float4 ov;
    ov.x = (acc[j]   - m) * rs * gv.x + bv.x;
    ov.y = (acc[j+1] - m) * rs * gv.y + bv.y;
    ov.z = (acc[j+2] - m) * rs * gv.z + bv.z;
    ov.w = (acc[j+3] - m) * rs * gv.w + bv.w;
    *(float4*)(orow + j) = ov;
  }
}

// ---------------- mean over O ----------------
__global__ __launch_bounds__(256) void k_reduce_oenc(const float* __restrict__ H2,
                                                     float* __restrict__ OENC) {
  int b = blockIdx.x, t = threadIdx.x;
  float s = 0.f;
  for (int o = 0; o < 50; ++o) s += H2[((size_t)b * 50 + o) * 256 + t];
  OENC[(size_t)b * 256 + t] = s * 0.02f;
}

// ---------------- temporal encoder + final classifier ----------------
__global__ __launch_bounds__(128) void k_heads(
    const float* __restrict__ daysb, const float* __restrict__ dayss,
    const float* __restrict__ te1_w, const float* __restrict__ te1_b,
    const float* __restrict__ ln1g, const float* __restrict__ ln1b,
    const float* __restrict__ te2_w, const float* __restrict__ te2_b,
    const float* __restrict__ ln2g, const float* __restrict__ ln2b,
    const float* __restrict__ OENC, const float* __restrict__ cWT /*[320][128]*/,
    const float* __restrict__ c_b, const float* __restrict__ clng,
    const float* __restrict__ clnb, float* __restrict__ out)
{
  __shared__ float feat[2];
  __shared__ float s1[32], s2[64], pre[128], stat[2];
  int b = blockIdx.x, t = threadIdx.x;
  if (t == 0) {
    float f0 = 0.f;
    for (int i = 0; i < 10; ++i) f0 += daysb[b * 10 + i];
    feat[0] = f0 * 0.1f;
    feat[1] = dayss[b];
  }
  __syncthreads();
  if (t < 32) s1[t] = te1_b[t] + feat[0] * te1_w[2 * t] + feat[1] * te1_w[2 * t + 1];
  __syncthreads();
  if (t == 0) {
    float s = 0.f; for (int j = 0; j < 32; ++j) s += s1[j];
    float m = s * (1.f / 32.f);
    float v = 0.f; for (int j = 0; j < 32; ++j) { float d = s1[j] - m; v += d * d; }
    stat[0] = m; stat[1] = rsqrtf(v * (1.f / 32.f) + 1e-5f);
  }
  __syncthreads();
  if (t < 32) s1[t] = fmaxf((s1[t] - stat[0]) * stat[1] * ln1g[t] + ln1b[t], 0.f);
  __syncthreads();
  if (t < 64) {
    float a = te2_b[t];
    for (int k = 0; k < 32; ++k) a += s1[k] * te2_w[t * 32 + k];
    s2[t] = a;
  }
  __syncthreads();
  if (t == 0) {
    float s = 0.f; for (int j = 0; j < 64; ++j) s += s2[j];
    float m = s * (1.f / 64.f);
    float v = 0.f; for (int j = 0; j < 64; ++j) { float d = s2[j] - m; v += d * d; }
    stat[0] = m; stat[1] = rsqrtf(v * (1.f / 64.f) + 1e-5f);
  }
  __syncthreads();
  if (t < 64) s2[t] = fmaxf((s2[t] - stat[0]) * stat[1] * ln2g[t] + ln2b[t], 0.f);
  __syncthreads();
  {
    float p = c_b[t];
    const float* oe = OENC + (size_t)b * 256;
    for (int k = 0; k < 256; ++k) p += oe[k] * cWT[k * 128 + t];
    for (int k = 0; k < 64; ++k)  p += s2[k] * cWT[(256 + k) * 128 + t];
    pre[t] = p;
  }
  __syncthreads();
  if (t == 0) {
    float s = 0.f; for (int j = 0; j < 128; ++j) s += pre[j];
    float m = s * (1.f / 128.f);
    float v = 0.f; for (int j = 0; j < 128; ++j) { float d = pre[j] - m; v += d * d; }
    stat[0] = m; stat[1] = rsqrtf(v * (1.f / 128.f) + 1e-5f);
  }
  __syncthreads();
  out[(size_t)b * 128 + t] = fmaxf((pre[t] - stat[0]) * stat[1] * clng[t] + clnb[t], 0.f);
}

// ---------------- host launcher ----------------
extern "C" void kernel_launch(void* const* d_in, const int* in_sizes, int n_in,
                              void* d_out, int out_size, void* d_ws, size_t ws_size,
                              hipStream_t stream)
{
  const int*   oh       = (const int*)d_in[0];
  const float* daysb    = (const float*)d_in[1];
  const float* dayss    = (const float*)d_in[2];
  const float* emb      = (const float*)d_in[3];
  const float* ia_in_w  = (const float*)d_in[4];
  const float* ia_in_b  = (const float*)d_in[5];
  const float* ia_out_w = (const float*)d_in[6];
  const float* ia_out_b = (const float*)d_in[7];
  const float* gf_wi = (const float*)d_in[8];
  const float* gf_wh = (const float*)d_in[9];
  const float* gf_bi = (const float*)d_in[10];
  const float* gf_bh = (const float*)d_in[11];
  const float* gb_wi = (const float*)d_in[12];
  const float* gb_wh = (const float*)d_in[13];
  const float* gb_bi = (const float*)d_in[14];
  const float* gb_bh = (const float*)d_in[15];
  const float* ta_in_w  = (const float*)d_in[16];
  const float* ta_in_b  = (const float*)d_in[17];
  const float* ta_out_w = (const float*)d_in[18];
  const float* ta_out_b = (const float*)d_in[19];
  const float* t_ln1_g = (const float*)d_in[20];
  const float* t_ln1_b = (const float*)d_in[21];
  const float* t_ln2_g = (const float*)d_in[22];
  const float* t_ln2_b = (const float*)d_in[23];
  const float* t_ff1_w = (const float*)d_in[24];
  const float* t_ff1_b = (const float*)d_in[25];
  const float* t_ff2_w = (const float*)d_in[26];
  const float* t_ff2_b = (const float*)d_in[27];
  const float* te1_w = (const float*)d_in[28];
  const float* te1_b = (const float*)d_in[29];
  const float* te_ln1_g = (const float*)d_in[30];
  const float* te_ln1_b = (const float*)d_in[31];
  const float* te2_w = (const float*)d_in[32];
  const float* te2_b = (const float*)d_in[33];
  const float* te_ln2_g = (const float*)d_in[34];
  const float* te_ln2_b = (const float*)d_in[35];
  const float* c_w   = (const float*)d_in[36];
  const float* c_b   = (const float*)d_in[37];
  const float* c_ln_g = (const float*)d_in[38];
  const float* c_ln_b = (const float*)d_in[39];

  float* ws = (float*)d_ws;
  const size_t OFF_X    = 0;                      // [O][B][64]   3,276,800
  const size_t OFF_G    = 3276800;                // [B][O][256] 13,107,200
  const size_t OFF_ATT  = OFF_G + 13107200;       // [B][O][256] 13,107,200
  const size_t OFF_OENC = OFF_ATT + 13107200;     // [B][256]       262,144
  const size_t OFF_WT   = OFF_OENC + 262144;
  const size_t TOTAL    = OFF_WT + 729088;        // ~122 MB
  if (ws_size < TOTAL * sizeof(float)) return;    // workspace too small; fail loudly

  float* X    = ws + OFF_X;
  float* Gbuf = ws + OFF_G;
  float* ATTb = ws + OFF_ATT;
  float* OENC = ws + OFF_OENC;
  float* w_ia_in  = ws + OFF_WT + 0;        // [64][192]
  float* w_ia_out = ws + OFF_WT + 12288;    // [64][64]
  float* w_gf_wi  = ws + OFF_WT + 16384;    // [64][384]
  float* w_gf_wh  = ws + OFF_WT + 40960;    // [128][384]
  float* w_gb_wi  = ws + OFF_WT + 90112;    // [64][384]
  float* w_gb_wh  = ws + OFF_WT + 114688;   // [128][384]
  float* w_ta_in  = ws + OFF_WT + 163840;   // [256][768]
  float* w_ta_out = ws + OFF_WT + 360448;   // [256][256]
  float* w_ff1    = ws + OFF_WT + 425984;   // [256][512]
  float* w_ff2    = ws + OFF_WT + 557056;   // [512][256]
  float* w_c      = ws + OFF_WT + 688128;   // [320][128]

  // weight transposes (coalesced inner-k reads downstream)
  #define TR(SRC, DST, R, C) k_transpose<<<((R)*(C)+255)/256, 256, 0, stream>>>(SRC, DST, R, C)
  TR(ia_in_w,  w_ia_in,  192, 64);
  TR(ia_out_w, w_ia_out, 64, 64);
  TR(gf_wi, w_gf_wi, 384, 64);
  TR(gf_wh, w_gf_wh, 384, 128);
  TR(gb_wi, w_gb_wi, 384, 64);
  TR(gb_wh, w_gb_wh, 384, 128);
  TR(ta_in_w,  w_ta_in,  768, 256);
  TR(ta_out_w, w_ta_out, 256, 256);
  TR(t_ff1_w, w_ff1, 512, 256);
  TR(t_ff2_w, w_ff2, 256, 512);
  TR(c_w, w_c, 128, 320);
  #undef TR

  k_item_attn<<<B_ * O_, 320, 0, stream>>>(oh, emb, w_ia_in, ia_in_b, w_ia_out, ia_out_b, X);
  k_gru<<<256, 256, 0, stream>>>(X, w_gf_wi, w_gf_wh, gf_bi, gf_bh,
                                 w_gb_wi, w_gb_wh, gb_bi, gb_bh, Gbuf);
  k_t_attn<<<B_ * 4, 384, 0, stream>>>(Gbuf, w_ta_in, ta_in_b, ATTb);
  k_t_out_ln<<<B_ * O_ / 16, 256, 0, stream>>>(Gbuf, ATTb, w_ta_out, ta_out_b, t_ln1_g, t_ln1_b);
  k_t_ffn<<<B_ * O_ / 16, 256, 0, stream>>>(ATTb, Gbuf, w_ff1, t_ff1_b, w_ff2, t_ff2_b,
                                            t_ln2_g, t_ln2_b);
  k_reduce_oenc<<<B_, 256, 0, stream>>>(Gbuf, OENC);
  k_heads<<<B_, 128, 0, stream>>>(daysb, dayss, te1_w, te1_b, te_ln1_g, te_ln1_b,
                                  te2_w, te2_b, te_ln2_g, te_ln2_b,
                                  OENC, w_c, c_b, c_ln_g, c_ln_b, (float*)d_out);
}

// Round 2
// 3495.243 us; speedup vs baseline: 1.7867x; 1.7867x over previous
//
#include <hip/hip_runtime.h>

// NextBasketEncoder — round 2: wave-per-pair item attention (mean-through-AV
// trick), 12-wave GRU, canonical 64x64 LDS-tiled fp32 GEMM for all transformer
// matmuls, fused residual+LN kernel, batch-chunked stride-768 scratch region.
// B=1024, O=50, L=20, D=64, H=128, DM=256, FF=512, V=49688.

#define B_ 1024
#define O_ 50
#define CB 256            // batch chunk for transformer stages
#define CROWS (CB * O_)   // 12800 rows per chunk

__device__ __forceinline__ float sig_(float x)  { return 1.0f / (1.0f + __expf(-x)); }
__device__ __forceinline__ float tanh_(float x) { return 2.0f / (1.0f + __expf(-2.0f * x)) - 1.0f; }

// ---------------- generic transpose: src[R][C] -> dst[C][R] ----------------
__global__ void k_transpose(const float* __restrict__ src, float* __restrict__ dst, int R, int C) {
  int i = blockIdx.x * 256 + threadIdx.x;
  if (i < R * C) {
    int r = i / C, c = i - r * C;
    dst[c * R + r] = src[i];
  }
}

// ---------------- stage 1: gather + item MHA + mean + proj ----------------
// one WAVE per (b,o); 4 waves (256 thr) per block. Mean-over-L is pushed
// through AV: only softmax column-sums are needed, AV matrix never formed.
// Weights read in original (col-major-for-our-dot) layout -> contiguous k.
__global__ __launch_bounds__(256) void k_item_attn(
    const int* __restrict__ oh, const float* __restrict__ emb,
    const float* __restrict__ wqkv /*ia_in_w [192][64]*/, const float* __restrict__ bqkv,
    const float* __restrict__ wo /*ia_out_w [64][64]*/, const float* __restrict__ bob,
    float* __restrict__ X /*[B*O][64]*/)
{
  __shared__ __align__(16) float Es[4][20][68];
  __shared__ __align__(16) float Qh[4][20][20], Kh[4][20][20], Vh[4][20][20];
  __shared__ float P[4][20][21];
  __shared__ float cs[4][20];
  __shared__ __align__(16) float meanA[4][68];

  int wv = threadIdx.x >> 6, lane = threadIdx.x & 63;
  int bo = blockIdx.x * 4 + wv;

  // gather: 20 embedding rows, coalesced 64-wide
  int idxv = (lane < 20) ? oh[bo * 20 + lane] : 0;
  for (int i = 0; i < 20; ++i) {
    int idx = __shfl(idxv, i, 64);
    Es[wv][i][lane] = emb[(size_t)idx * 64 + lane];
  }
  int rg = lane >> 4, cg = lane & 15;
  __syncthreads();

  for (int h = 0; h < 4; ++h) {
    // qkv for this head: lane (rg,cg) -> rows {rg,rg+4,..,rg+16}, col cg
    float aq[5], ak[5], av[5];
    {
      float bq = bqkv[h * 16 + cg], bk = bqkv[64 + h * 16 + cg], bv = bqkv[128 + h * 16 + cg];
#pragma unroll
      for (int m = 0; m < 5; ++m) { aq[m] = bq; ak[m] = bk; av[m] = bv; }
    }
    const float* wqp = &wqkv[(size_t)(h * 16 + cg) * 64];
    const float* wkp = &wqkv[(size_t)(64 + h * 16 + cg) * 64];
    const float* wvp = &wqkv[(size_t)(128 + h * 16 + cg) * 64];
    for (int k = 0; k < 64; k += 4) {
      float4 wq = *(const float4*)(wqp + k);
      float4 wk = *(const float4*)(wkp + k);
      float4 wvv = *(const float4*)(wvp + k);
#pragma unroll
      for (int m = 0; m < 5; ++m) {
        float4 e = *(const float4*)&Es[wv][rg + 4 * m][k];
        aq[m] += e.x * wq.x + e.y * wq.y + e.z * wq.z + e.w * wq.w;
        ak[m] += e.x * wk.x + e.y * wk.y + e.z * wk.z + e.w * wk.w;
        av[m] += e.x * wvv.x + e.y * wvv.y + e.z * wvv.z + e.w * wvv.w;
      }
    }
#pragma unroll
    for (int m = 0; m < 5; ++m) {
      Qh[wv][rg + 4 * m][cg] = aq[m];
      Kh[wv][rg + 4 * m][cg] = ak[m];
      Vh[wv][rg + 4 * m][cg] = av[m];
    }
    __syncthreads();

    // scores 20x20, hd=16, scale 0.25
    for (int e = lane; e < 400; e += 64) {
      int i = e / 20, j = e - (e / 20) * 20;
      const float* qp = &Qh[wv][i][0];
      const float* kp = &Kh[wv][j][0];
      float d = 0.f;
#pragma unroll
      for (int k = 0; k < 16; k += 4) {
        float4 q = *(const float4*)(qp + k);
        float4 kk = *(const float4*)(kp + k);
        d += q.x * kk.x + q.y * kk.y + q.z * kk.z + q.w * kk.w;
      }
      P[wv][i][j] = d * 0.25f;
    }
    __syncthreads();

    // row softmax
    if (lane < 20) {
      int i = lane;
      float m = -1e30f;
      for (int j = 0; j < 20; ++j) m = fmaxf(m, P[wv][i][j]);
      float s = 0.f;
      for (int j = 0; j < 20; ++j) { float v = __expf(P[wv][i][j] - m); P[wv][i][j] = v; s += v; }
      float inv = 1.f / s;
      for (int j = 0; j < 20; ++j) P[wv][i][j] *= inv;
    }
    __syncthreads();

    // column sums (mean-through-AV), fold 1/20
    if (lane < 20) {
      int j = lane;
      float s = 0.f;
      for (int i = 0; i < 20; ++i) s += P[wv][i][j];
      cs[wv][j] = s * 0.05f;
    }
    __syncthreads();

    // meanATT[h*16+c] = sum_j cs[j] * V[j][c]
    if (lane < 16) {
      float a = 0.f;
      for (int j = 0; j < 20; ++j) a += cs[wv][j] * Vh[wv][j][lane];
      meanA[wv][h * 16 + lane] = a;
    }
    __syncthreads();
  }

  // out-proj of the mean (commutes): lane owns one output col
  float acc = bob[lane];
  const float* wrow = &wo[(size_t)lane * 64];
  for (int k = 0; k < 64; k += 4) {
    float4 m4 = *(const float4*)&meanA[wv][k];
    float4 w4 = *(const float4*)(wrow + k);
    acc += m4.x * w4.x + m4.y * w4.y + m4.z * w4.z + m4.w * w4.w;
  }
  X[(size_t)bo * 64 + lane] = acc;
}

// ---------------- stage 2: bidirectional GRU ----------------
// 256 blocks (128 row-groups x 2 dirs), 768 threads = 12 waves/CU.
// thread = (r = t/96 row, cg = t%96 -> 4 gate cols of 384).
__global__ __launch_bounds__(768) void k_gru(
    const float* __restrict__ X /*[B*O][64]*/,
    const float* __restrict__ wiT_f /*[64][384]*/, const float* __restrict__ whT_f /*[128][384]*/,
    const float* __restrict__ bi_f, const float* __restrict__ bh_f,
    const float* __restrict__ wiT_b, const float* __restrict__ whT_b,
    const float* __restrict__ bi_b, const float* __restrict__ bh_b,
    float* __restrict__ G /*[B*O][256]*/)
{
  __shared__ __align__(16) float hs[8][132];
  __shared__ __align__(16) float xs[8][68];
  __shared__ __align__(16) float AI[8][388], AH[8][388];

  int dir = blockIdx.x >> 7;
  int rb = (blockIdx.x & 127) * 8;
  const float* wiT = dir ? wiT_b : wiT_f;
  const float* whT = dir ? whT_b : whT_f;
  const float* bi  = dir ? bi_b : bi_f;
  const float* bh  = dir ? bh_b : bh_f;
  int t = threadIdx.x;
  int r = t / 96, cg = t - 96 * r, c0 = cg * 4;

  for (int e = t; e < 1024; e += 768) hs[e >> 7][e & 127] = 0.f;
  __syncthreads();

  float4 bi4 = *(const float4*)&bi[c0];
  float4 bh4 = *(const float4*)&bh[c0];

  for (int s = 0; s < 50; ++s) {
    int o = dir ? 49 - s : s;
    if (t < 512) xs[t >> 6][t & 63] = X[(size_t)((rb + (t >> 6)) * 50 + o) * 64 + (t & 63)];
    __syncthreads();

    float ai0 = bi4.x, ai1 = bi4.y, ai2 = bi4.z, ai3 = bi4.w;
    float ah0 = bh4.x, ah1 = bh4.y, ah2 = bh4.z, ah3 = bh4.w;
#pragma unroll 4
    for (int k = 0; k < 64; ++k) {
      float4 w = *(const float4*)&wiT[(size_t)k * 384 + c0];
      float x = xs[r][k];
      ai0 += x * w.x; ai1 += x * w.y; ai2 += x * w.z; ai3 += x * w.w;
    }
#pragma unroll 4
    for (int k = 0; k < 128; ++k) {
      float4 w = *(const float4*)&whT[(size_t)k * 384 + c0];
      float hv = hs[r][k];
      ah0 += hv * w.x; ah1 += hv * w.y; ah2 += hv * w.z; ah3 += hv * w.w;
    }
    *(float4*)&AI[r][c0] = make_float4(ai0, ai1, ai2, ai3);
    *(float4*)&AH[r][c0] = make_float4(ah0, ah1, ah2, ah3);
    __syncthreads();

    for (int e = t; e < 1024; e += 768) {
      int r2 = e >> 7, c = e & 127;
      float rr = sig_(AI[r2][c] + AH[r2][c]);
      float zz = sig_(AI[r2][128 + c] + AH[r2][128 + c]);
      float nn = tanh_(AI[r2][256 + c] + rr * AH[r2][256 + c]);
      float h2 = (1.f - zz) * nn + zz * hs[r2][c];
      hs[r2][c] = h2;
      G[(size_t)((rb + r2) * 50 + o) * 256 + dir * 128 + c] = h2;
    }
    __syncthreads();
  }
}

// ---------------- canonical fp32 tiled GEMM: C = A[M][K] * W[K][N] + bias ----
// 64x64 tile, BK=16, 256 threads, 4x4 acc/thread, both operands LDS-staged.
__global__ __launch_bounds__(256) void k_gemm64(
    const float* __restrict__ A, int lda,
    const float* __restrict__ W, int N,
    const float* __restrict__ bias,
    float* __restrict__ C, int ldc, int K, int relu)
{
  __shared__ __align__(16) float As[16][72];   // As[k][m] (transposed)
  __shared__ __align__(16) float Bs[16][72];   // Bs[k][n]
  int m0 = blockIdx.y * 64, n0 = blockIdx.x * 64;
  int tid = threadIdx.x;
  int aR = tid >> 2, aK = (tid & 3) * 4;
  int bK = tid >> 4, bN = (tid & 15) * 4;
  int tm = (tid >> 4) * 4, tn = (tid & 15) * 4;

  float acc[16];
#pragma unroll
  for (int i = 0; i < 16; ++i) acc[i] = 0.f;

  for (int k0 = 0; k0 < K; k0 += 16) {
    float4 a4 = *(const float4*)&A[(size_t)(m0 + aR) * lda + k0 + aK];
    float4 b4 = *(const float4*)&W[(size_t)(k0 + bK) * N + n0 + bN];
    __syncthreads();
    As[aK + 0][aR] = a4.x; As[aK + 1][aR] = a4.y; As[aK + 2][aR] = a4.z; As[aK + 3][aR] = a4.w;
    *(float4*)&Bs[bK][bN] = b4;
    __syncthreads();
#pragma unroll
    for (int k = 0; k < 16; ++k) {
      float4 av = *(const float4*)&As[k][tm];
      float4 bv = *(const float4*)&Bs[k][tn];
      acc[0]  += av.x * bv.x; acc[1]  += av.x * bv.y; acc[2]  += av.x * bv.z; acc[3]  += av.x * bv.w;
      acc[4]  += av.y * bv.x; acc[5]  += av.y * bv.y; acc[6]  += av.y * bv.z; acc[7]  += av.y * bv.w;
      acc[8]  += av.z * bv.x; acc[9]  += av.z * bv.y; acc[10] += av.z * bv.z; acc[11] += av.z * bv.w;
      acc[12] += av.w * bv.x; acc[13] += av.w * bv.y; acc[14] += av.w * bv.z; acc[15] += av.w * bv.w;
    }
  }

  float4 bb = *(const float4*)&bias[n0 + tn];
#pragma unroll
  for (int i = 0; i < 4; ++i) {
    float4 ov = make_float4(acc[i * 4 + 0] + bb.x, acc[i * 4 + 1] + bb.y,
                            acc[i * 4 + 2] + bb.z, acc[i * 4 + 3] + bb.w);
    if (relu) {
      ov.x = fmaxf(ov.x, 0.f); ov.y = fmaxf(ov.y, 0.f);
      ov.z = fmaxf(ov.z, 0.f); ov.w = fmaxf(ov.w, 0.f);
    }
    *(float4*)&C[(size_t)(m0 + tm + i) * ldc + n0 + tn] = ov;
  }
}

// ---------------- transformer attention core (reads precomputed QKV) --------
// one block per batch-row in chunk, loops 4 heads; writes ATT over q-section.
__global__ __launch_bounds__(256) void k_attn_core(float* __restrict__ BIG)
{
  __shared__ __align__(16) float qs[50][68], ks[50][68], vs[50][68];
  __shared__ float P[50][52];
  int bl = blockIdx.x, t = threadIdx.x;
  size_t base = (size_t)bl * 50 * 768;

  for (int h = 0; h < 4; ++h) {
    int hc = h * 64;
    for (int e = t; e < 3200; e += 256) { int row = e >> 6, c = e & 63; qs[row][c] = BIG[base + (size_t)row * 768 + hc + c]; }
    for (int e = t; e < 3200; e += 256) { int row = e >> 6, c = e & 63; ks[row][c] = BIG[base + (size_t)row * 768 + 256 + hc + c]; }
    for (int e = t; e < 3200; e += 256) { int row = e >> 6, c = e & 63; vs[row][c] = BIG[base + (size_t)row * 768 + 512 + hc + c]; }
    __syncthreads();

    for (int e = t; e < 2500; e += 256) {
      int i = e / 50, j = e - (e / 50) * 50;
      float d = 0.f;
#pragma unroll
      for (int k = 0; k < 64; k += 4) {
        float4 q = *(const float4*)&qs[i][k];
        float4 kk = *(const float4*)&ks[j][k];
        d += q.x * kk.x + q.y * kk.y + q.z * kk.z + q.w * kk.w;
      }
      P[i][j] = d * 0.125f;
    }
    __syncthreads();

    if (t < 50) {
      float m = -1e30f;
      for (int j = 0; j < 50; ++j) m = fmaxf(m, P[t][j]);
      float s = 0.f;
      for (int j = 0; j < 50; ++j) { float v = __expf(P[t][j] - m); P[t][j] = v; s += v; }
      float inv = 1.f / s;
      for (int j = 0; j < 50; ++j) P[t][j] *= inv;
    }
    __syncthreads();

    for (int e = t; e < 3200; e += 256) {
      int i = e >> 6, c = e & 63;
      float a = 0.f;
      for (int j = 0; j < 50; ++j) a += P[i][j] * vs[j][c];
      BIG[base + (size_t)i * 768 + hc + c] = a;   // overwrite q-section (already consumed)
    }
    __syncthreads();
  }
}

// ---------------- fused residual + LayerNorm (wave per row, in-place safe) ---
__global__ __launch_bounds__(256) void k_ln_res(
    const float* __restrict__ res, const float* __restrict__ add, int addld,
    float* __restrict__ dst, const float* __restrict__ g, const float* __restrict__ bt)
{
  int row = blockIdx.x * 4 + (threadIdx.x >> 6);
  int lane = threadIdx.x & 63;
  int c = lane * 4;
  float4 rv = *(const float4*)&res[(size_t)row * 256 + c];
  float4 av = *(const float4*)&add[(size_t)row * addld + c];
  float x0 = rv.x + av.x, x1 = rv.y + av.y, x2 = rv.z + av.z, x3 = rv.w + av.w;
  float s = x0 + x1 + x2 + x3;
  float sq = x0 * x0 + x1 * x1 + x2 * x2 + x3 * x3;
#pragma unroll
  for (int d = 1; d < 64; d <<= 1) { s += __shfl_xor(s, d, 64); sq += __shfl_xor(sq, d, 64); }
  float m = s * (1.f / 256.f);
  float var = sq * (1.f / 256.f) - m * m;
  float rs = rsqrtf(var + 1e-5f);
  float4 gv = *(const float4*)&g[c];
  float4 bv = *(const float4*)&bt[c];
  float4 ov;
  ov.x = (x0 - m) * rs * gv.x + bv.x;
  ov.y = (x1 - m) * rs * gv.y + bv.y;
  ov.z = (x2 - m) * rs * gv.z + bv.z;
  ov.w = (x3 - m) * rs * gv.w + bv.w;
  *(float4*)&dst[(size_t)row * 256 + c] = ov;
}

// ---------------- mean over O ----------------
__global__ __launch_bounds__(256) void k_reduce_oenc(const float* __restrict__ H2,
                                                     float* __restrict__ OENC) {
  int b = blockIdx.x, t = threadIdx.x;
  float s = 0.f;
  for (int o = 0; o < 50; ++o) s += H2[((size_t)b * 50 + o) * 256 + t];
  OENC[(size_t)b * 256 + t] = s * 0.02f;
}

// ---------------- temporal encoder + final classifier ----------------
__global__ __launch_bounds__(128) void k_heads(
    const float* __restrict__ daysb, const float* __restrict__ dayss,
    const float* __restrict__ te1_w, const float* __restrict__ te1_b,
    const float* __restrict__ ln1g, const float* __restrict__ ln1b,
    const float* __restrict__ te2_w, const float* __restrict__ te2_b,
    const float* __restrict__ ln2g, const float* __restrict__ ln2b,
    const float* __restrict__ OENC, const float* __restrict__ cWT /*[320][128]*/,
    const float* __restrict__ c_b, const float* __restrict__ clng,
    const float* __restrict__ clnb, float* __restrict__ out)
{
  __shared__ float feat[2];
  __shared__ float s1[32], s2[64], pre[128], stat[2];
  int b = blockIdx.x, t = threadIdx.x;
  if (t == 0) {
    float f0 = 0.f;
    for (int i = 0; i < 10; ++i) f0 += daysb[b * 10 + i];
    feat[0] = f0 * 0.1f;
    feat[1] = dayss[b];
  }
  __syncthreads();
  if (t < 32) s1[t] = te1_b[t] + feat[0] * te1_w[2 * t] + feat[1] * te1_w[2 * t + 1];
  __syncthreads();
  if (t == 0) {
    float s = 0.f; for (int j = 0; j < 32; ++j) s += s1[j];
    float m = s * (1.f / 32.f);
    float v = 0.f; for (int j = 0; j < 32; ++j) { float d = s1[j] - m; v += d * d; }
    stat[0] = m; stat[1] = rsqrtf(v * (1.f / 32.f) + 1e-5f);
  }
  __syncthreads();
  if (t < 32) s1[t] = fmaxf((s1[t] - stat[0]) * stat[1] * ln1g[t] + ln1b[t], 0.f);
  __syncthreads();
  if (t < 64) {
    float a = te2_b[t];
    for (int k = 0; k < 32; ++k) a += s1[k] * te2_w[t * 32 + k];
    s2[t] = a;
  }
  __syncthreads();
  if (t == 0) {
    float s = 0.f; for (int j = 0; j < 64; ++j) s += s2[j];
    float m = s * (1.f / 64.f);
    float v = 0.f; for (int j = 0; j < 64; ++j) { float d = s2[j] - m; v += d * d; }
    stat[0] = m; stat[1] = rsqrtf(v * (1.f / 64.f) + 1e-5f);
  }
  __syncthreads();
  if (t < 64) s2[t] = fmaxf((s2[t] - stat[0]) * stat[1] * ln2g[t] + ln2b[t], 0.f);
  __syncthreads();
  {
    float p = c_b[t];
    const float* oe = OENC + (size_t)b * 256;
    for (int k = 0; k < 256; ++k) p += oe[k] * cWT[k * 128 + t];
    for (int k = 0; k < 64; ++k)  p += s2[k] * cWT[(256 + k) * 128 + t];
    pre[t] = p;
  }
  __syncthreads();
  if (t == 0) {
    float s = 0.f; for (int j = 0; j < 128; ++j) s += pre[j];
    float m = s * (1.f / 128.f);
    float v = 0.f; for (int j = 0; j < 128; ++j) { float d = pre[j] - m; v += d * d; }
    stat[0] = m; stat[1] = rsqrtf(v * (1.f / 128.f) + 1e-5f);
  }
  __syncthreads();
  out[(size_t)b * 128 + t] = fmaxf((pre[t] - stat[0]) * stat[1] * clng[t] + clnb[t], 0.f);
}

// ---------------- host launcher ----------------
extern "C" void kernel_launch(void* const* d_in, const int* in_sizes, int n_in,
                              void* d_out, int out_size, void* d_ws, size_t ws_size,
                              hipStream_t stream)
{
  const int*   oh       = (const int*)d_in[0];
  const float* daysb    = (const float*)d_in[1];
  const float* dayss    = (const float*)d_in[2];
  const float* emb      = (const float*)d_in[3];
  const float* ia_in_w  = (const float*)d_in[4];
  const float* ia_in_b  = (const float*)d_in[5];
  const float* ia_out_w = (const float*)d_in[6];
  const float* ia_out_b = (const float*)d_in[7];
  const float* gf_wi = (const float*)d_in[8];
  const float* gf_wh = (const float*)d_in[9];
  const float* gf_bi = (const float*)d_in[10];
  const float* gf_bh = (const float*)d_in[11];
  const float* gb_wi = (const float*)d_in[12];
  const float* gb_wh = (const float*)d_in[13];
  const float* gb_bi = (const float*)d_in[14];
  const float* gb_bh = (const float*)d_in[15];
  const float* ta_in_w  = (const float*)d_in[16];
  const float* ta_in_b  = (const float*)d_in[17];
  const float* ta_out_w = (const float*)d_in[18];
  const float* ta_out_b = (const float*)d_in[19];
  const float* t_ln1_g = (const float*)d_in[20];
  const float* t_ln1_b = (const float*)d_in[21];
  const float* t_ln2_g = (const float*)d_in[22];
  const float* t_ln2_b = (const float*)d_in[23];
  const float* t_ff1_w = (const float*)d_in[24];
  const float* t_ff1_b = (const float*)d_in[25];
  const float* t_ff2_w = (const float*)d_in[26];
  const float* t_ff2_b = (const float*)d_in[27];
  const float* te1_w = (const float*)d_in[28];
  const float* te1_b = (const float*)d_in[29];
  const float* te_ln1_g = (const float*)d_in[30];
  const float* te_ln1_b = (const float*)d_in[31];
  const float* te2_w = (const float*)d_in[32];
  const float* te2_b = (const float*)d_in[33];
  const float* te_ln2_g = (const float*)d_in[34];
  const float* te_ln2_b = (const float*)d_in[35];
  const float* c_w   = (const float*)d_in[36];
  const float* c_b   = (const float*)d_in[37];
  const float* c_ln_g = (const float*)d_in[38];
  const float* c_ln_b = (const float*)d_in[39];

  float* ws = (float*)d_ws;
  const size_t OFF_X    = 0;                        // [B*O][64]    3,276,800
  const size_t OFF_G    = 3276800;                  // [B*O][256]  13,107,200
  const size_t OFF_BIG  = OFF_G + 13107200;         // [12800][768] 9,830,400
  const size_t OFF_OENC = OFF_BIG + 9830400;        // [B][256]       262,144
  const size_t OFF_WT   = OFF_OENC + 262144;
  const size_t TOTAL    = OFF_WT + 712704;          // ~108.8 MB (< round-1's 122 MB)
  if (ws_size < TOTAL * sizeof(float)) return;

  float* X    = ws + OFF_X;
  float* Gbuf = ws + OFF_G;
  float* BIG  = ws + OFF_BIG;
  float* OENC = ws + OFF_OENC;
  float* w_gf_wi  = ws + OFF_WT + 0;        // [64][384]
  float* w_gf_wh  = ws + OFF_WT + 24576;    // [128][384]
  float* w_gb_wi  = ws + OFF_WT + 73728;    // [64][384]
  float* w_gb_wh  = ws + OFF_WT + 98304;    // [128][384]
  float* w_ta_in  = ws + OFF_WT + 147456;   // [256][768]
  float* w_ta_out = ws + OFF_WT + 344064;   // [256][256]
  float* w_ff1    = ws + OFF_WT + 409600;   // [256][512]
  float* w_ff2    = ws + OFF_WT + 540672;   // [512][256]
  float* w_c      = ws + OFF_WT + 671744;   // [320][128]

  #define TR(SRC, DST, R, C) k_transpose<<<((R)*(C)+255)/256, 256, 0, stream>>>(SRC, DST, R, C)
  TR(gf_wi, w_gf_wi, 384, 64);
  TR(gf_wh, w_gf_wh, 384, 128);
  TR(gb_wi, w_gb_wi, 384, 64);
  TR(gb_wh, w_gb_wh, 384, 128);
  TR(ta_in_w,  w_ta_in,  768, 256);
  TR(ta_out_w, w_ta_out, 256, 256);
  TR(t_ff1_w, w_ff1, 512, 256);
  TR(t_ff2_w, w_ff2, 256, 512);
  TR(c_w, w_c, 128, 320);
  #undef TR

  k_item_attn<<<B_ * O_ / 4, 256, 0, stream>>>(oh, emb, ia_in_w, ia_in_b, ia_out_w, ia_out_b, X);
  k_gru<<<256, 768, 0, stream>>>(X, w_gf_wi, w_gf_wh, gf_bi, gf_bh,
                                 w_gb_wi, w_gb_wh, gb_bi, gb_bh, Gbuf);

  for (int c = 0; c < B_ / CB; ++c) {
    float* Gc = Gbuf + (size_t)c * CROWS * 256;
    // QKV projection -> BIG[12800][768]
    k_gemm64<<<dim3(768 / 64, CROWS / 64), 256, 0, stream>>>(Gc, 256, w_ta_in, 768, ta_in_b, BIG, 768, 256, 0);
    // attention core (per b, 4-head loop); ATT overwrites q-section
    k_attn_core<<<CB, 256, 0, stream>>>(BIG);
    // out-proj: ATT (cols 0..255) -> O1 (cols 256..511)
    k_gemm64<<<dim3(256 / 64, CROWS / 64), 256, 0, stream>>>(BIG, 768, w_ta_out, 256, ta_out_b, BIG + 256, 768, 256, 0);
    // LN1: H1 = LN(G + O1), in place over G
    k_ln_res<<<CROWS / 4, 256, 0, stream>>>(Gc, BIG + 256, 768, Gc, t_ln1_g, t_ln1_b);
    // FFN1 (+ReLU): H1 -> cols 0..511 of BIG
    k_gemm64<<<dim3(512 / 64, CROWS / 64), 256, 0, stream>>>(Gc, 256, w_ff1, 512, t_ff1_b, BIG, 768, 256, 1);
    // FFN2: -> O2 (cols 512..767)
    k_gemm64<<<dim3(256 / 64, CROWS / 64), 256, 0, stream>>>(BIG, 768, w_ff2, 256, t_ff2_b, BIG + 512, 768, 512, 0);
    // LN2: H2 = LN(H1 + O2), in place over G
    k_ln_res<<<CROWS / 4, 256, 0, stream>>>(Gc, BIG + 512, 768, Gc, t_ln2_g, t_ln2_b);
  }

  k_reduce_oenc<<<B_, 256, 0, stream>>>(Gbuf, OENC);
  k_heads<<<B_, 128, 0, stream>>>(daysb, dayss, te1_w, te1_b, te_ln1_g, te_ln1_b,
                                  te2_w, te2_b, te_ln2_g, te_ln2_b,
                                  OENC, w_c, c_b, c_ln_g, c_ln_b, (float*)d_out);
}

// Round 3
// 2128.957 us; speedup vs baseline: 2.9334x; 1.6418x over previous
//
#include <hip/hip_runtime.h>

// NextBasketEncoder — round 3: bf16 MFMA GEMM primitive (gather-fused variant
// for item QKV), fp32 activations with in-staging bf16 conversion, per-(b,head)
// transformer attention, phase-aliased workspace (117.6 MB).
// B=1024, O=50, L=20, D=64, H=128, DM=256, FF=512, V=49688.

#define B_ 1024
#define O_ 50
#define CB 128                 // transformer batch chunk
#define CROWS (CB * O_)        // 6400 rows
#define IP 6400                // item-attn pair chunk (8 chunks)
#define IROWS (IP * 20)        // 128000 gathered rows

typedef __attribute__((ext_vector_type(8))) short  short8v;
typedef __attribute__((ext_vector_type(8))) unsigned short ushort8v;
typedef __attribute__((ext_vector_type(4))) float f32x4;

__device__ __forceinline__ float sig_(float x)  { return 1.0f / (1.0f + __expf(-x)); }
__device__ __forceinline__ float tanh_(float x) { return 2.0f / (1.0f + __expf(-2.0f * x)) - 1.0f; }

__device__ __forceinline__ unsigned short f2bf(float f) {
  union { float f; unsigned int u; } v; v.f = f;
  unsigned int r = v.u + 0x7FFFu + ((v.u >> 16) & 1u);   // RNE
  return (unsigned short)(r >> 16);
}
__device__ __forceinline__ float bf2f(unsigned short u) {
  union { unsigned int u; float f; } v; v.u = ((unsigned int)u) << 16;
  return v.f;
}

// ---------------- generic transpose: src[R][C] -> dst[C][R] ----------------
__global__ void k_transpose(const float* __restrict__ src, float* __restrict__ dst, int R, int C) {
  int i = blockIdx.x * 256 + threadIdx.x;
  if (i < R * C) {
    int r = i / C, c = i - r * C;
    dst[c * R + r] = src[i];
  }
}

// ---------------- fp32 -> bf16 elementwise ----------------
__global__ void k_f32bf16(const float* __restrict__ src, unsigned short* __restrict__ dst, int n) {
  int i = blockIdx.x * 256 + threadIdx.x;
  if (i < n) dst[i] = f2bf(src[i]);
}

// ---------------- bf16 MFMA GEMM: C[M][N] = A[M][K] @ Wb[N][K]^T + bias -----
// 64x64 tile, BK=32, 256 thr = 4 waves (2x2), 2x2 16x16x32 frags per wave.
// A fp32 (converted in staging); GATHER: A row r = emb[gidx[m0+r]] (K=64).
template<int GATHER, int RELU, int OBF>
__global__ __launch_bounds__(256) void k_gemm_mfma(
    const float* __restrict__ A, int lda,
    const int* __restrict__ gidx, const float* __restrict__ emb,
    const unsigned short* __restrict__ Wb, int K,
    const float* __restrict__ bias,
    float* __restrict__ Cf, unsigned short* __restrict__ Cb, int ldc)
{
  __shared__ unsigned short As[64][40];   // [row][k], pad to 40 (80B stride)
  __shared__ unsigned short Bs[64][40];   // [ncol][k]
  int n0 = blockIdx.x * 64, m0 = blockIdx.y * 64;
  int t = threadIdx.x;
  int srow = t >> 2, skq = (t & 3) * 8;
  int wv = t >> 6, lane = t & 63;
  int wr = wv >> 1, wc = wv & 1;
  int fr = lane & 15, kg = lane >> 4;

  f32x4 acc00 = {0.f,0.f,0.f,0.f}, acc01 = {0.f,0.f,0.f,0.f};
  f32x4 acc10 = {0.f,0.f,0.f,0.f}, acc11 = {0.f,0.f,0.f,0.f};

  const float* arow;
  if (GATHER) arow = &emb[(size_t)gidx[m0 + srow] * 64];
  else        arow = &A[(size_t)(m0 + srow) * lda];
  const unsigned short* brow = &Wb[(size_t)(n0 + srow) * K];

  for (int k0 = 0; k0 < K; k0 += 32) {
    float4 a0 = *(const float4*)(arow + k0 + skq);
    float4 a1 = *(const float4*)(arow + k0 + skq + 4);
    ushort8v bv = *(const ushort8v*)(brow + k0 + skq);
    __syncthreads();
    ushort8v ap;
    ap[0] = f2bf(a0.x); ap[1] = f2bf(a0.y); ap[2] = f2bf(a0.z); ap[3] = f2bf(a0.w);
    ap[4] = f2bf(a1.x); ap[5] = f2bf(a1.y); ap[6] = f2bf(a1.z); ap[7] = f2bf(a1.w);
    *(ushort8v*)&As[srow][skq] = ap;
    *(ushort8v*)&Bs[srow][skq] = bv;
    __syncthreads();
    short8v af0 = *(const short8v*)&As[wr * 32 + fr][kg * 8];
    short8v af1 = *(const short8v*)&As[wr * 32 + 16 + fr][kg * 8];
    short8v bf0 = *(const short8v*)&Bs[wc * 32 + fr][kg * 8];
    short8v bf1 = *(const short8v*)&Bs[wc * 32 + 16 + fr][kg * 8];
    acc00 = __builtin_amdgcn_mfma_f32_16x16x32_bf16(af0, bf0, acc00, 0, 0, 0);
    acc01 = __builtin_amdgcn_mfma_f32_16x16x32_bf16(af0, bf1, acc01, 0, 0, 0);
    acc10 = __builtin_amdgcn_mfma_f32_16x16x32_bf16(af1, bf0, acc10, 0, 0, 0);
    acc11 = __builtin_amdgcn_mfma_f32_16x16x32_bf16(af1, bf1, acc11, 0, 0, 0);
  }

  // epilogue: C row = m0 + wr*32 + mi*16 + kg*4 + r ; col = n0 + wc*32 + ni*16 + fr
#pragma unroll
  for (int mi = 0; mi < 2; ++mi) {
#pragma unroll
    for (int ni = 0; ni < 2; ++ni) {
      f32x4 a = (mi == 0) ? (ni == 0 ? acc00 : acc01) : (ni == 0 ? acc10 : acc11);
      int col = n0 + wc * 32 + ni * 16 + fr;
      float bb = bias[col];
#pragma unroll
      for (int r = 0; r < 4; ++r) {
        int row = m0 + wr * 32 + mi * 16 + kg * 4 + r;
        float v = a[r] + bb;
        if (RELU) v = fmaxf(v, 0.f);
        if (OBF) Cb[(size_t)row * ldc + col] = f2bf(v);
        else     Cf[(size_t)row * ldc + col] = v;
      }
    }
  }
}

// ---------------- item attention core (QKV precomputed, bf16) ----------------
// one wave per pair; scores/softmax/colsum (mean-through-AV) + out-proj.
__global__ __launch_bounds__(256) void k_item_core(
    const unsigned short* __restrict__ QKV /*[IROWS][192] bf16*/,
    const float* __restrict__ wo /*[64][64]*/, const float* __restrict__ bob,
    float* __restrict__ Xc /*[IP][64]*/)
{
  __shared__ __align__(16) float QS[4][20][196];
  __shared__ float P[4][20][21];
  __shared__ float cs[4][20];
  __shared__ float meanA[4][68];

  int wv = threadIdx.x >> 6, lane = threadIdx.x & 63;
  int p = blockIdx.x * 4 + wv;
  const unsigned short* src = QKV + (size_t)p * 20 * 192;

  for (int e = lane; e < 3840; e += 64) {
    int row = e / 192, c = e - row * 192;
    QS[wv][row][c] = bf2f(src[(size_t)row * 192 + c]);
  }
  __syncwarp();

  for (int h = 0; h < 4; ++h) {
    int qc = h * 16, kc = 64 + h * 16, vc = 128 + h * 16;
    // scores 20x20 (dot-16), scale 0.25
    for (int e = lane; e < 400; e += 64) {
      int i = e / 20, j = e - (e / 20) * 20;
      float d = 0.f;
#pragma unroll
      for (int k = 0; k < 16; k += 4) {
        float4 q = *(const float4*)&QS[wv][i][qc + k];
        float4 kk = *(const float4*)&QS[wv][j][kc + k];
        d += q.x * kk.x + q.y * kk.y + q.z * kk.z + q.w * kk.w;
      }
      P[wv][i][j] = d * 0.25f;
    }
    __syncwarp();
    if (lane < 20) {
      int i = lane;
      float m = -1e30f;
      for (int j = 0; j < 20; ++j) m = fmaxf(m, P[wv][i][j]);
      float s = 0.f;
      for (int j = 0; j < 20; ++j) { float v = __expf(P[wv][i][j] - m); P[wv][i][j] = v; s += v; }
      float inv = 1.f / s;
      for (int j = 0; j < 20; ++j) P[wv][i][j] *= inv;
    }
    __syncwarp();
    if (lane < 20) {      // column sums, fold mean 1/20
      int j = lane;
      float s = 0.f;
      for (int i = 0; i < 20; ++i) s += P[wv][i][j];
      cs[wv][j] = s * 0.05f;
    }
    __syncwarp();
    if (lane < 16) {      // meanATT[h*16+c] = sum_j cs[j] V[j][c]
      float a = 0.f;
      for (int j = 0; j < 20; ++j) a += cs[wv][j] * QS[wv][j][vc + lane];
      meanA[wv][h * 16 + lane] = a;
    }
    __syncwarp();
  }

  float acc = bob[lane];
  const float* wrow = &wo[(size_t)lane * 64];
  for (int k = 0; k < 64; k += 4) {
    float4 m4 = *(const float4*)&meanA[wv][k];
    float4 w4 = *(const float4*)(wrow + k);
    acc += m4.x * w4.x + m4.y * w4.y + m4.z * w4.z + m4.w * w4.w;
  }
  Xc[(size_t)p * 64 + lane] = acc;
}

// ---------------- bidirectional GRU (unchanged from round 2) ----------------
__global__ __launch_bounds__(768) void k_gru(
    const float* __restrict__ X /*[B*O][64]*/,
    const float* __restrict__ wiT_f, const float* __restrict__ whT_f,
    const float* __restrict__ bi_f, const float* __restrict__ bh_f,
    const float* __restrict__ wiT_b, const float* __restrict__ whT_b,
    const float* __restrict__ bi_b, const float* __restrict__ bh_b,
    float* __restrict__ G /*[B*O][256]*/)
{
  __shared__ __align__(16) float hs[8][132];
  __shared__ __align__(16) float xs[8][68];
  __shared__ __align__(16) float AI[8][388], AH[8][388];

  int dir = blockIdx.x >> 7;
  int rb = (blockIdx.x & 127) * 8;
  const float* wiT = dir ? wiT_b : wiT_f;
  const float* whT = dir ? whT_b : whT_f;
  const float* bi  = dir ? bi_b : bi_f;
  const float* bh  = dir ? bh_b : bh_f;
  int t = threadIdx.x;
  int r = t / 96, cg = t - 96 * r, c0 = cg * 4;

  for (int e = t; e < 1024; e += 768) hs[e >> 7][e & 127] = 0.f;
  __syncthreads();

  float4 bi4 = *(const float4*)&bi[c0];
  float4 bh4 = *(const float4*)&bh[c0];

  for (int s = 0; s < 50; ++s) {
    int o = dir ? 49 - s : s;
    if (t < 512) xs[t >> 6][t & 63] = X[(size_t)((rb + (t >> 6)) * 50 + o) * 64 + (t & 63)];
    __syncthreads();

    float ai0 = bi4.x, ai1 = bi4.y, ai2 = bi4.z, ai3 = bi4.w;
    float ah0 = bh4.x, ah1 = bh4.y, ah2 = bh4.z, ah3 = bh4.w;
#pragma unroll 4
    for (int k = 0; k < 64; ++k) {
      float4 w = *(const float4*)&wiT[(size_t)k * 384 + c0];
      float x = xs[r][k];
      ai0 += x * w.x; ai1 += x * w.y; ai2 += x * w.z; ai3 += x * w.w;
    }
#pragma unroll 4
    for (int k = 0; k < 128; ++k) {
      float4 w = *(const float4*)&whT[(size_t)k * 384 + c0];
      float hv = hs[r][k];
      ah0 += hv * w.x; ah1 += hv * w.y; ah2 += hv * w.z; ah3 += hv * w.w;
    }
    *(float4*)&AI[r][c0] = make_float4(ai0, ai1, ai2, ai3);
    *(float4*)&AH[r][c0] = make_float4(ah0, ah1, ah2, ah3);
    __syncthreads();

    for (int e = t; e < 1024; e += 768) {
      int r2 = e >> 7, c = e & 127;
      float rr = sig_(AI[r2][c] + AH[r2][c]);
      float zz = sig_(AI[r2][128 + c] + AH[r2][128 + c]);
      float nn = tanh_(AI[r2][256 + c] + rr * AH[r2][256 + c]);
      float h2 = (1.f - zz) * nn + zz * hs[r2][c];
      hs[r2][c] = h2;
      G[(size_t)((rb + r2) * 50 + o) * 256 + dir * 128 + c] = h2;
    }
    __syncthreads();
  }
}

// ---------------- transformer attention core: one block per (b,head) --------
__global__ __launch_bounds__(256) void k_attn_core(
    const float* __restrict__ QKV /*[CROWS][768]*/, float* __restrict__ ATT /*[CROWS][256]*/)
{
  __shared__ __align__(16) float qs[50][68], ks[50][68], vs[50][68];
  __shared__ float P[50][52];
  int bl = blockIdx.x >> 2, h = blockIdx.x & 3;
  int t = threadIdx.x;
  size_t base = (size_t)bl * 50 * 768;
  int hc = h * 64;

  for (int e = t; e < 3200; e += 256) { int row = e >> 6, c = e & 63; qs[row][c] = QKV[base + (size_t)row * 768 + hc + c]; }
  for (int e = t; e < 3200; e += 256) { int row = e >> 6, c = e & 63; ks[row][c] = QKV[base + (size_t)row * 768 + 256 + hc + c]; }
  for (int e = t; e < 3200; e += 256) { int row = e >> 6, c = e & 63; vs[row][c] = QKV[base + (size_t)row * 768 + 512 + hc + c]; }
  __syncthreads();

  for (int e = t; e < 2500; e += 256) {
    int i = e / 50, j = e - (e / 50) * 50;
    float d = 0.f;
#pragma unroll
    for (int k = 0; k < 64; k += 4) {
      float4 q = *(const float4*)&qs[i][k];
      float4 kk = *(const float4*)&ks[j][k];
      d += q.x * kk.x + q.y * kk.y + q.z * kk.z + q.w * kk.w;
    }
    P[i][j] = d * 0.125f;
  }
  __syncthreads();
  if (t < 50) {
    float m = -1e30f;
    for (int j = 0; j < 50; ++j) m = fmaxf(m, P[t][j]);
    float s = 0.f;
    for (int j = 0; j < 50; ++j) { float v = __expf(P[t][j] - m); P[t][j] = v; s += v; }
    float inv = 1.f / s;
    for (int j = 0; j < 50; ++j) P[t][j] *= inv;
  }
  __syncthreads();
  for (int e = t; e < 3200; e += 256) {
    int i = e >> 6, c = e & 63;
    float a = 0.f;
    for (int j = 0; j < 50; ++j) a += P[i][j] * vs[j][c];
    ATT[(size_t)(bl * 50 + i) * 256 + hc + c] = a;
  }
}

// ---------------- fused residual + LayerNorm (wave per row) ----------------
__global__ __launch_bounds__(256) void k_ln_res(
    const float* __restrict__ res, const float* __restrict__ add, int addld,
    float* __restrict__ dst, const float* __restrict__ g, const float* __restrict__ bt)
{
  int row = blockIdx.x * 4 + (threadIdx.x >> 6);
  int lane = threadIdx.x & 63;
  int c = lane * 4;
  float4 rv = *(const float4*)&res[(size_t)row * 256 + c];
  float4 av = *(const float4*)&add[(size_t)row * addld + c];
  float x0 = rv.x + av.x, x1 = rv.y + av.y, x2 = rv.z + av.z, x3 = rv.w + av.w;
  float s = x0 + x1 + x2 + x3;
  float sq = x0 * x0 + x1 * x1 + x2 * x2 + x3 * x3;
#pragma unroll
  for (int d = 1; d < 64; d <<= 1) { s += __shfl_xor(s, d, 64); sq += __shfl_xor(sq, d, 64); }
  float m = s * (1.f / 256.f);
  float var = sq * (1.f / 256.f) - m * m;
  float rs = rsqrtf(var + 1e-5f);
  float4 gv = *(const float4*)&g[c];
  float4 bv = *(const float4*)&bt[c];
  float4 ov;
  ov.x = (x0 - m) * rs * gv.x + bv.x;
  ov.y = (x1 - m) * rs * gv.y + bv.y;
  ov.z = (x2 - m) * rs * gv.z + bv.z;
  ov.w = (x3 - m) * rs * gv.w + bv.w;
  *(float4*)&dst[(size_t)row * 256 + c] = ov;
}

// ---------------- mean over O ----------------
__global__ __launch_bounds__(256) void k_reduce_oenc(const float* __restrict__ H2,
                                                     float* __restrict__ OENC) {
  int b = blockIdx.x, t = threadIdx.x;
  float s = 0.f;
  for (int o = 0; o < 50; ++o) s += H2[((size_t)b * 50 + o) * 256 + t];
  OENC[(size_t)b * 256 + t] = s * 0.02f;
}

// ---------------- temporal encoder + final classifier ----------------
__global__ __launch_bounds__(128) void k_heads(
    const float* __restrict__ daysb, const float* __restrict__ dayss,
    const float* __restrict__ te1_w, const float* __restrict__ te1_b,
    const float* __restrict__ ln1g, const float* __restrict__ ln1b,
    const float* __restrict__ te2_w, const float* __restrict__ te2_b,
    const float* __restrict__ ln2g, const float* __restrict__ ln2b,
    const float* __restrict__ OENC, const float* __restrict__ cWT /*[320][128]*/,
    const float* __restrict__ c_b, const float* __restrict__ clng,
    const float* __restrict__ clnb, float* __restrict__ out)
{
  __shared__ float feat[2];
  __shared__ float s1[32], s2[64], pre[128], stat[2];
  int b = blockIdx.x, t = threadIdx.x;
  if (t == 0) {
    float f0 = 0.f;
    for (int i = 0; i < 10; ++i) f0 += daysb[b * 10 + i];
    feat[0] = f0 * 0.1f;
    feat[1] = dayss[b];
  }
  __syncthreads();
  if (t < 32) s1[t] = te1_b[t] + feat[0] * te1_w[2 * t] + feat[1] * te1_w[2 * t + 1];
  __syncthreads();
  if (t == 0) {
    float s = 0.f; for (int j = 0; j < 32; ++j) s += s1[j];
    float m = s * (1.f / 32.f);
    float v = 0.f; for (int j = 0; j < 32; ++j) { float d = s1[j] - m; v += d * d; }
    stat[0] = m; stat[1] = rsqrtf(v * (1.f / 32.f) + 1e-5f);
  }
  __syncthreads();
  if (t < 32) s1[t] = fmaxf((s1[t] - stat[0]) * stat[1] * ln1g[t] + ln1b[t], 0.f);
  __syncthreads();
  if (t < 64) {
    float a = te2_b[t];
    for (int k = 0; k < 32; ++k) a += s1[k] * te2_w[t * 32 + k];
    s2[t] = a;
  }
  __syncthreads();
  if (t == 0) {
    float s = 0.f; for (int j = 0; j < 64; ++j) s += s2[j];
    float m = s * (1.f / 64.f);
    float v = 0.f; for (int j = 0; j < 64; ++j) { float d = s2[j] - m; v += d * d; }
    stat[0] = m; stat[1] = rsqrtf(v * (1.f / 64.f) + 1e-5f);
  }
  __syncthreads();
  if (t < 64) s2[t] = fmaxf((s2[t] - stat[0]) * stat[1] * ln2g[t] + ln2b[t], 0.f);
  __syncthreads();
  {
    float p = c_b[t];
    const float* oe = OENC + (size_t)b * 256;
    for (int k = 0; k < 256; ++k) p += oe[k] * cWT[k * 128 + t];
    for (int k = 0; k < 64; ++k)  p += s2[k] * cWT[(256 + k) * 128 + t];
    pre[t] = p;
  }
  __syncthreads();
  if (t == 0) {
    float s = 0.f; for (int j = 0; j < 128; ++j) s += pre[j];
    float m = s * (1.f / 128.f);
    float v = 0.f; for (int j = 0; j < 128; ++j) { float d = pre[j] - m; v += d * d; }
    stat[0] = m; stat[1] = rsqrtf(v * (1.f / 128.f) + 1e-5f);
  }
  __syncthreads();
  out[(size_t)b * 128 + t] = fmaxf((pre[t] - stat[0]) * stat[1] * clng[t] + clnb[t], 0.f);
}

// ---------------- host launcher ----------------
extern "C" void kernel_launch(void* const* d_in, const int* in_sizes, int n_in,
                              void* d_out, int out_size, void* d_ws, size_t ws_size,
                              hipStream_t stream)
{
  const int*   oh       = (const int*)d_in[0];
  const float* daysb    = (const float*)d_in[1];
  const float* dayss    = (const float*)d_in[2];
  const float* emb      = (const float*)d_in[3];
  const float* ia_in_w  = (const float*)d_in[4];
  const float* ia_in_b  = (const float*)d_in[5];
  const float* ia_out_w = (const float*)d_in[6];
  const float* ia_out_b = (const float*)d_in[7];
  const float* gf_wi = (const float*)d_in[8];
  const float* gf_wh = (const float*)d_in[9];
  const float* gf_bi = (const float*)d_in[10];
  const float* gf_bh = (const float*)d_in[11];
  const float* gb_wi = (const float*)d_in[12];
  const float* gb_wh = (const float*)d_in[13];
  const float* gb_bi = (const float*)d_in[14];
  const float* gb_bh = (const float*)d_in[15];
  const float* ta_in_w  = (const float*)d_in[16];
  const float* ta_in_b  = (const float*)d_in[17];
  const float* ta_out_w = (const float*)d_in[18];
  const float* ta_out_b = (const float*)d_in[19];
  const float* t_ln1_g = (const float*)d_in[20];
  const float* t_ln1_b = (const float*)d_in[21];
  const float* t_ln2_g = (const float*)d_in[22];
  const float* t_ln2_b = (const float*)d_in[23];
  const float* t_ff1_w = (const float*)d_in[24];
  const float* t_ff1_b = (const float*)d_in[25];
  const float* t_ff2_w = (const float*)d_in[26];
  const float* t_ff2_b = (const float*)d_in[27];
  const float* te1_w = (const float*)d_in[28];
  const float* te1_b = (const float*)d_in[29];
  const float* te_ln1_g = (const float*)d_in[30];
  const float* te_ln1_b = (const float*)d_in[31];
  const float* te2_w = (const float*)d_in[32];
  const float* te2_b = (const float*)d_in[33];
  const float* te_ln2_g = (const float*)d_in[34];
  const float* te_ln2_b = (const float*)d_in[35];
  const float* c_w   = (const float*)d_in[36];
  const float* c_b   = (const float*)d_in[37];
  const float* c_ln_g = (const float*)d_in[38];
  const float* c_ln_b = (const float*)d_in[39];

  float* ws = (float*)d_ws;
  // layout (floats):
  const size_t OFF_G    = 0;                       // [B*O][256] fp32  13,107,200
  const size_t OFF_S2   = 13107200;                // phase-aliased slot 15,564,800
  const size_t OFF_OENC = OFF_S2 + 15564800;       // [B][256]            262,144
  const size_t OFF_W    = OFF_OENC + 262144;
  // fp32 transposed (GRU + classifier):
  const size_t OW_GFWI = OFF_W;                    // 24,576
  const size_t OW_GFWH = OW_GFWI + 24576;          // 49,152
  const size_t OW_GBWI = OW_GFWH + 49152;          // 24,576
  const size_t OW_GBWH = OW_GBWI + 24576;          // 49,152
  const size_t OW_C    = OW_GBWH + 49152;          // 40,960
  const size_t OW_BF   = OW_C + 40960;             // bf16 pool: 536,576 ushort = 268,288 fl
  const size_t TOTAL   = OW_BF + 268288;           // 29,390,848 floats = 117.6 MB
  if (ws_size < TOTAL * sizeof(float)) return;

  float* Gbuf = ws + OFF_G;
  float* OENC = ws + OFF_OENC;
  float* w_gf_wi = ws + OW_GFWI;
  float* w_gf_wh = ws + OW_GFWH;
  float* w_gb_wi = ws + OW_GBWI;
  float* w_gb_wh = ws + OW_GBWH;
  float* w_c     = ws + OW_C;
  unsigned short* bfp = (unsigned short*)(ws + OW_BF);
  unsigned short* b_ta_in  = bfp;                  // 196,608
  unsigned short* b_ta_out = b_ta_in + 196608;     //  65,536
  unsigned short* b_ff1    = b_ta_out + 65536;     // 131,072
  unsigned short* b_ff2    = b_ff1 + 131072;       // 131,072
  unsigned short* b_ia_in  = b_ff2 + 131072;       //  12,288

  // phase 1 (item stage): QKVbf [IROWS][192] bf16 + X [B*O][64] fp32
  unsigned short* QKVbf = (unsigned short*)(ws + OFF_S2);   // 24,576,000 ushort
  float* X = ws + OFF_S2 + 12288000;                        // 3,276,800 fl
  // phase 2 (transformer, aliases the QKVbf region):
  float* BIG = ws + OFF_S2;                // [6400][768] 4,915,200
  float* ATTb = BIG + 4915200;             // [6400][256] 1,638,400
  float* F1  = ATTb + 1638400;             // [6400][512] 3,276,800  (O1 aliases start)
  float* O1  = F1;
  float* O2  = F1 + 3276800;               // [6400][256] 1,638,400

  #define TR(SRC, DST, R, C) k_transpose<<<((R)*(C)+255)/256, 256, 0, stream>>>(SRC, DST, R, C)
  TR(gf_wi, w_gf_wi, 384, 64);
  TR(gf_wh, w_gf_wh, 384, 128);
  TR(gb_wi, w_gb_wi, 384, 64);
  TR(gb_wh, w_gb_wh, 384, 128);
  TR(c_w, w_c, 128, 320);
  #undef TR
  #define CV(SRC, DST, N) k_f32bf16<<<((N)+255)/256, 256, 0, stream>>>(SRC, DST, N)
  CV(ta_in_w,  b_ta_in,  196608);
  CV(ta_out_w, b_ta_out, 65536);
  CV(t_ff1_w,  b_ff1,    131072);
  CV(t_ff2_w,  b_ff2,    131072);
  CV(ia_in_w,  b_ia_in,  12288);
  #undef CV

  // ---- item attention: 8 chunks of IP pairs ----
  for (int ci = 0; ci < (B_ * O_) / IP; ++ci) {
    k_gemm_mfma<1, 0, 1><<<dim3(192 / 64, IROWS / 64), 256, 0, stream>>>(
        nullptr, 0, oh + (size_t)ci * IROWS, emb, b_ia_in, 64, ia_in_b,
        nullptr, QKVbf, 192);
    k_item_core<<<IP / 4, 256, 0, stream>>>(QKVbf, ia_out_w, ia_out_b, X + (size_t)ci * IP * 64);
  }

  // ---- bidirectional GRU ----
  k_gru<<<256, 768, 0, stream>>>(X, w_gf_wi, w_gf_wh, gf_bi, gf_bh,
                                 w_gb_wi, w_gb_wh, gb_bi, gb_bh, Gbuf);

  // ---- transformer layer: 8 chunks of CB batch rows ----
  for (int c = 0; c < B_ / CB; ++c) {
    float* Gc = Gbuf + (size_t)c * CROWS * 256;
    k_gemm_mfma<0, 0, 0><<<dim3(768 / 64, CROWS / 64), 256, 0, stream>>>(
        Gc, 256, nullptr, nullptr, b_ta_in, 256, ta_in_b, BIG, nullptr, 768);
    k_attn_core<<<CB * 4, 256, 0, stream>>>(BIG, ATTb);
    k_gemm_mfma<0, 0, 0><<<dim3(256 / 64, CROWS / 64), 256, 0, stream>>>(
        ATTb, 256, nullptr, nullptr, b_ta_out, 256, ta_out_b, O1, nullptr, 256);
    k_ln_res<<<CROWS / 4, 256, 0, stream>>>(Gc, O1, 256, Gc, t_ln1_g, t_ln1_b);
    k_gemm_mfma<0, 1, 0><<<dim3(512 / 64, CROWS / 64), 256, 0, stream>>>(
        Gc, 256, nullptr, nullptr, b_ff1, 256, t_ff1_b, F1, nullptr, 512);
    k_gemm_mfma<0, 0, 0><<<dim3(256 / 64, CROWS / 64), 256, 0, stream>>>(
        F1, 512, nullptr, nullptr, b_ff2, 512, t_ff2_b, O2, nullptr, 256);
    k_ln_res<<<CROWS / 4, 256, 0, stream>>>(Gc, O2, 256, Gc, t_ln2_g, t_ln2_b);
  }

  k_reduce_oenc<<<B_, 256, 0, stream>>>(Gbuf, OENC);
  k_heads<<<B_, 128, 0, stream>>>(daysb, dayss, te1_w, te1_b, te_ln1_g, te_ln1_b,
                                  te2_w, te2_b, te_ln2_g, te_ln2_b,
                                  OENC, w_c, c_b, c_ln_g, c_ln_b, (float*)d_out);
}

// Round 4
// 1348.156 us; speedup vs baseline: 4.6323x; 1.5792x over previous
//
#include <hip/hip_runtime.h>

// NextBasketEncoder — round 4: GRU rebuilt as register-resident-weight MFMA
// recurrence with precomputed input gates (GI) via bf16 GEMM. Item/transformer
// stages unchanged from round 3. Workspace 117.3 MB.
// B=1024, O=50, L=20, D=64, H=128, DM=256, FF=512, V=49688.

#define B_ 1024
#define O_ 50
#define CB 128                 // transformer batch chunk
#define CROWS (CB * O_)        // 6400 rows
#define IP 6400                // item-attn pair chunk (8 chunks)
#define IROWS (IP * 20)        // 128000 gathered rows
#define GCHUNK 512             // GRU batch-row chunk (2 chunks)
#define GROWS (GCHUNK * O_)    // 25600 GI rows per chunk

typedef __attribute__((ext_vector_type(8))) short  short8v;
typedef __attribute__((ext_vector_type(8))) unsigned short ushort8v;
typedef __attribute__((ext_vector_type(4))) float f32x4;

__device__ __forceinline__ float sig_(float x)  { return 1.0f / (1.0f + __expf(-x)); }
__device__ __forceinline__ float tanh_(float x) { return 2.0f / (1.0f + __expf(-2.0f * x)) - 1.0f; }

__device__ __forceinline__ unsigned short f2bf(float f) {
  union { float f; unsigned int u; } v; v.f = f;
  unsigned int r = v.u + 0x7FFFu + ((v.u >> 16) & 1u);   // RNE
  return (unsigned short)(r >> 16);
}
__device__ __forceinline__ float bf2f(unsigned short u) {
  union { unsigned int u; float f; } v; v.u = ((unsigned int)u) << 16;
  return v.f;
}

// ---------------- generic transpose: src[R][C] -> dst[C][R] ----------------
__global__ void k_transpose(const float* __restrict__ src, float* __restrict__ dst, int R, int C) {
  int i = blockIdx.x * 256 + threadIdx.x;
  if (i < R * C) {
    int r = i / C, c = i - r * C;
    dst[c * R + r] = src[i];
  }
}

// ---------------- fp32 -> bf16 elementwise ----------------
__global__ void k_f32bf16(const float* __restrict__ src, unsigned short* __restrict__ dst, int n) {
  int i = blockIdx.x * 256 + threadIdx.x;
  if (i < n) dst[i] = f2bf(src[i]);
}

// ---------------- bf16 MFMA GEMM: C[M][N] = A[M][K] @ Wb[N][K]^T + bias -----
// 64x64 tile, BK=32, 256 thr = 4 waves (2x2), 2x2 16x16x32 frags per wave.
// A fp32 (converted in staging); GATHER: A row r = emb[gidx[m0+r]] (K=64).
template<int GATHER, int RELU, int OBF>
__global__ __launch_bounds__(256) void k_gemm_mfma(
    const float* __restrict__ A, int lda,
    const int* __restrict__ gidx, const float* __restrict__ emb,
    const unsigned short* __restrict__ Wb, int K,
    const float* __restrict__ bias,
    float* __restrict__ Cf, unsigned short* __restrict__ Cb, int ldc)
{
  __shared__ unsigned short As[64][40];   // [row][k], pad to 40 (80B stride)
  __shared__ unsigned short Bs[64][40];   // [ncol][k]
  int n0 = blockIdx.x * 64, m0 = blockIdx.y * 64;
  int t = threadIdx.x;
  int srow = t >> 2, skq = (t & 3) * 8;
  int wv = t >> 6, lane = t & 63;
  int wr = wv >> 1, wc = wv & 1;
  int fr = lane & 15, kg = lane >> 4;

  f32x4 acc00 = {0.f,0.f,0.f,0.f}, acc01 = {0.f,0.f,0.f,0.f};
  f32x4 acc10 = {0.f,0.f,0.f,0.f}, acc11 = {0.f,0.f,0.f,0.f};

  const float* arow;
  if (GATHER) arow = &emb[(size_t)gidx[m0 + srow] * 64];
  else        arow = &A[(size_t)(m0 + srow) * lda];
  const unsigned short* brow = &Wb[(size_t)(n0 + srow) * K];

  for (int k0 = 0; k0 < K; k0 += 32) {
    float4 a0 = *(const float4*)(arow + k0 + skq);
    float4 a1 = *(const float4*)(arow + k0 + skq + 4);
    ushort8v bv = *(const ushort8v*)(brow + k0 + skq);
    __syncthreads();
    ushort8v ap;
    ap[0] = f2bf(a0.x); ap[1] = f2bf(a0.y); ap[2] = f2bf(a0.z); ap[3] = f2bf(a0.w);
    ap[4] = f2bf(a1.x); ap[5] = f2bf(a1.y); ap[6] = f2bf(a1.z); ap[7] = f2bf(a1.w);
    *(ushort8v*)&As[srow][skq] = ap;
    *(ushort8v*)&Bs[srow][skq] = bv;
    __syncthreads();
    short8v af0 = *(const short8v*)&As[wr * 32 + fr][kg * 8];
    short8v af1 = *(const short8v*)&As[wr * 32 + 16 + fr][kg * 8];
    short8v bf0 = *(const short8v*)&Bs[wc * 32 + fr][kg * 8];
    short8v bf1 = *(const short8v*)&Bs[wc * 32 + 16 + fr][kg * 8];
    acc00 = __builtin_amdgcn_mfma_f32_16x16x32_bf16(af0, bf0, acc00, 0, 0, 0);
    acc01 = __builtin_amdgcn_mfma_f32_16x16x32_bf16(af0, bf1, acc01, 0, 0, 0);
    acc10 = __builtin_amdgcn_mfma_f32_16x16x32_bf16(af1, bf0, acc10, 0, 0, 0);
    acc11 = __builtin_amdgcn_mfma_f32_16x16x32_bf16(af1, bf1, acc11, 0, 0, 0);
  }

  // epilogue: C row = m0 + wr*32 + mi*16 + kg*4 + r ; col = n0 + wc*32 + ni*16 + fr
#pragma unroll
  for (int mi = 0; mi < 2; ++mi) {
#pragma unroll
    for (int ni = 0; ni < 2; ++ni) {
      f32x4 a = (mi == 0) ? (ni == 0 ? acc00 : acc01) : (ni == 0 ? acc10 : acc11);
      int col = n0 + wc * 32 + ni * 16 + fr;
      float bb = bias[col];
#pragma unroll
      for (int r = 0; r < 4; ++r) {
        int row = m0 + wr * 32 + mi * 16 + kg * 4 + r;
        float v = a[r] + bb;
        if (RELU) v = fmaxf(v, 0.f);
        if (OBF) Cb[(size_t)row * ldc + col] = f2bf(v);
        else     Cf[(size_t)row * ldc + col] = v;
      }
    }
  }
}

// ---------------- item attention core (QKV precomputed, bf16) ----------------
__global__ __launch_bounds__(256) void k_item_core(
    const unsigned short* __restrict__ QKV /*[IROWS][192] bf16*/,
    const float* __restrict__ wo /*[64][64]*/, const float* __restrict__ bob,
    float* __restrict__ Xc /*[IP][64]*/)
{
  __shared__ __align__(16) float QS[4][20][196];
  __shared__ float P[4][20][21];
  __shared__ float cs[4][20];
  __shared__ float meanA[4][68];

  int wv = threadIdx.x >> 6, lane = threadIdx.x & 63;
  int p = blockIdx.x * 4 + wv;
  const unsigned short* src = QKV + (size_t)p * 20 * 192;

  for (int e = lane; e < 3840; e += 64) {
    int row = e / 192, c = e - row * 192;
    QS[wv][row][c] = bf2f(src[(size_t)row * 192 + c]);
  }
  __syncwarp();

  for (int h = 0; h < 4; ++h) {
    int qc = h * 16, kc = 64 + h * 16, vc = 128 + h * 16;
    for (int e = lane; e < 400; e += 64) {
      int i = e / 20, j = e - (e / 20) * 20;
      float d = 0.f;
#pragma unroll
      for (int k = 0; k < 16; k += 4) {
        float4 q = *(const float4*)&QS[wv][i][qc + k];
        float4 kk = *(const float4*)&QS[wv][j][kc + k];
        d += q.x * kk.x + q.y * kk.y + q.z * kk.z + q.w * kk.w;
      }
      P[wv][i][j] = d * 0.25f;
    }
    __syncwarp();
    if (lane < 20) {
      int i = lane;
      float m = -1e30f;
      for (int j = 0; j < 20; ++j) m = fmaxf(m, P[wv][i][j]);
      float s = 0.f;
      for (int j = 0; j < 20; ++j) { float v = __expf(P[wv][i][j] - m); P[wv][i][j] = v; s += v; }
      float inv = 1.f / s;
      for (int j = 0; j < 20; ++j) P[wv][i][j] *= inv;
    }
    __syncwarp();
    if (lane < 20) {
      int j = lane;
      float s = 0.f;
      for (int i = 0; i < 20; ++i) s += P[wv][i][j];
      cs[wv][j] = s * 0.05f;
    }
    __syncwarp();
    if (lane < 16) {
      float a = 0.f;
      for (int j = 0; j < 20; ++j) a += cs[wv][j] * QS[wv][j][vc + lane];
      meanA[wv][h * 16 + lane] = a;
    }
    __syncwarp();
  }

  float acc = bob[lane];
  const float* wrow = &wo[(size_t)lane * 64];
  for (int k = 0; k < 64; k += 4) {
    float4 m4 = *(const float4*)&meanA[wv][k];
    float4 w4 = *(const float4*)(wrow + k);
    acc += m4.x * w4.x + m4.y * w4.y + m4.z * w4.z + m4.w * w4.w;
  }
  Xc[(size_t)p * 64 + lane] = acc;
}

// ---------------- GRU recurrence: register-resident Wh, MFMA, 4 rows/block ---
// 512 thr = 8 waves; wave w owns gate-cols [w*48, w*48+48). GI (= x@Wi+bi)
// precomputed bf16 [GROWS][384]. 50 sequential steps; h bf16 in LDS for MFMA A,
// h_old fp32 in the owning thread's register.
__global__ __launch_bounds__(512) void k_gru_mfma(
    const unsigned short* __restrict__ GIf, const unsigned short* __restrict__ GIb,
    const unsigned short* __restrict__ whf /*[384][128] bf16*/,
    const unsigned short* __restrict__ whb,
    const float* __restrict__ bh_f, const float* __restrict__ bh_b,
    float* __restrict__ G /*chunk-offset [GCHUNK*O_][256]*/)
{
  __shared__ unsigned short hsb[16][136];   // bf16 h, rows 4-15 stay zero
  __shared__ float ah[4][392];

  int bid = blockIdx.x;
  int dir = bid >> 7;            // 128 row-groups per dir
  int rg  = bid & 127;
  const unsigned short* GI = dir ? GIb : GIf;
  const unsigned short* wh = dir ? whb : whf;
  const float* bh = dir ? bh_b : bh_f;

  int t = threadIdx.x;
  int w = t >> 6, lane = t & 63;
  int fr = lane & 15, kg = lane >> 4;

  // B fragments: col = w*48 + n*16 + fr, k = kf*32 + kg*8  (stay in VGPRs)
  short8v bfr[3][4];
#pragma unroll
  for (int n = 0; n < 3; ++n)
#pragma unroll
    for (int kf = 0; kf < 4; ++kf)
      bfr[n][kf] = *(const short8v*)&wh[(size_t)(w * 48 + n * 16 + fr) * 128 + kf * 32 + kg * 8];

  for (int e = t; e < 16 * 136; e += 512) ((unsigned short*)hsb)[e] = 0;

  // gate-thread mapping: row = t>>7 (0..3), col c = t&127
  int grow = t >> 7, gc = t & 127;
  float bh0 = bh[gc], bh1 = bh[128 + gc], bh2 = bh[256 + gc];
  float hold = 0.f;
  const unsigned short* gip = &GI[(size_t)(rg * 4 + grow) * 50 * 384];
  float* gout = &G[((size_t)(rg * 4 + grow) * 50) * 256 + dir * 128 + gc];

  __syncthreads();

  int o0 = dir ? 49 : 0;
  unsigned short c0v = gip[o0 * 384 + gc];
  unsigned short c1v = gip[o0 * 384 + 128 + gc];
  unsigned short c2v = gip[o0 * 384 + 256 + gc];

  for (int s = 0; s < 50; ++s) {
    int o  = dir ? 49 - s : s;
    unsigned short n0v = 0, n1v = 0, n2v = 0;
    if (s < 49) {
      int on = dir ? 48 - s : s + 1;
      n0v = gip[on * 384 + gc];
      n1v = gip[on * 384 + 128 + gc];
      n2v = gip[on * 384 + 256 + gc];
    }

    // A fragments from h (bf16)
    short8v a0 = *(const short8v*)&hsb[fr][0 * 32 + kg * 8];
    short8v a1 = *(const short8v*)&hsb[fr][1 * 32 + kg * 8];
    short8v a2 = *(const short8v*)&hsb[fr][2 * 32 + kg * 8];
    short8v a3 = *(const short8v*)&hsb[fr][3 * 32 + kg * 8];

    f32x4 acc0 = {0.f,0.f,0.f,0.f}, acc1 = {0.f,0.f,0.f,0.f}, acc2 = {0.f,0.f,0.f,0.f};
    acc0 = __builtin_amdgcn_mfma_f32_16x16x32_bf16(a0, bfr[0][0], acc0, 0, 0, 0);
    acc1 = __builtin_amdgcn_mfma_f32_16x16x32_bf16(a0, bfr[1][0], acc1, 0, 0, 0);
    acc2 = __builtin_amdgcn_mfma_f32_16x16x32_bf16(a0, bfr[2][0], acc2, 0, 0, 0);
    acc0 = __builtin_amdgcn_mfma_f32_16x16x32_bf16(a1, bfr[0][1], acc0, 0, 0, 0);
    acc1 = __builtin_amdgcn_mfma_f32_16x16x32_bf16(a1, bfr[1][1], acc1, 0, 0, 0);
    acc2 = __builtin_amdgcn_mfma_f32_16x16x32_bf16(a1, bfr[2][1], acc2, 0, 0, 0);
    acc0 = __builtin_amdgcn_mfma_f32_16x16x32_bf16(a2, bfr[0][2], acc0, 0, 0, 0);
    acc1 = __builtin_amdgcn_mfma_f32_16x16x32_bf16(a2, bfr[1][2], acc1, 0, 0, 0);
    acc2 = __builtin_amdgcn_mfma_f32_16x16x32_bf16(a2, bfr[2][2], acc2, 0, 0, 0);
    acc0 = __builtin_amdgcn_mfma_f32_16x16x32_bf16(a3, bfr[0][3], acc0, 0, 0, 0);
    acc1 = __builtin_amdgcn_mfma_f32_16x16x32_bf16(a3, bfr[1][3], acc1, 0, 0, 0);
    acc2 = __builtin_amdgcn_mfma_f32_16x16x32_bf16(a3, bfr[2][3], acc2, 0, 0, 0);

    if (kg == 0) {   // lanes 0-15 hold rows 0-3 (reg r -> row r)
#pragma unroll
      for (int r = 0; r < 4; ++r) {
        ah[r][w * 48 + 0 * 16 + fr] = acc0[r];
        ah[r][w * 48 + 1 * 16 + fr] = acc1[r];
        ah[r][w * 48 + 2 * 16 + fr] = acc2[r];
      }
    }
    __syncthreads();

    // gate math: one (row, col) per thread
    float ai0 = bf2f(c0v), ai1 = bf2f(c1v), ai2 = bf2f(c2v);
    float ah0 = ah[grow][gc] + bh0;
    float ah1 = ah[grow][128 + gc] + bh1;
    float ah2 = ah[grow][256 + gc] + bh2;
    float rr = sig_(ai0 + ah0);
    float zz = sig_(ai1 + ah1);
    float nn = tanh_(ai2 + rr * ah2);
    float h2 = (1.f - zz) * nn + zz * hold;
    hold = h2;
    hsb[grow][gc] = f2bf(h2);
    gout[(size_t)o * 256] = h2;
    c0v = n0v; c1v = n1v; c2v = n2v;
    __syncthreads();
  }
}

// ---------------- transformer attention core: one block per (b,head) --------
__global__ __launch_bounds__(256) void k_attn_core(
    const float* __restrict__ QKV /*[CROWS][768]*/, float* __restrict__ ATT /*[CROWS][256]*/)
{
  __shared__ __align__(16) float qs[50][68], ks[50][68], vs[50][68];
  __shared__ float P[50][52];
  int bl = blockIdx.x >> 2, h = blockIdx.x & 3;
  int t = threadIdx.x;
  size_t base = (size_t)bl * 50 * 768;
  int hc = h * 64;

  for (int e = t; e < 3200; e += 256) { int row = e >> 6, c = e & 63; qs[row][c] = QKV[base + (size_t)row * 768 + hc + c]; }
  for (int e = t; e < 3200; e += 256) { int row = e >> 6, c = e & 63; ks[row][c] = QKV[base + (size_t)row * 768 + 256 + hc + c]; }
  for (int e = t; e < 3200; e += 256) { int row = e >> 6, c = e & 63; vs[row][c] = QKV[base + (size_t)row * 768 + 512 + hc + c]; }
  __syncthreads();

  for (int e = t; e < 2500; e += 256) {
    int i = e / 50, j = e - (e / 50) * 50;
    float d = 0.f;
#pragma unroll
    for (int k = 0; k < 64; k += 4) {
      float4 q = *(const float4*)&qs[i][k];
      float4 kk = *(const float4*)&ks[j][k];
      d += q.x * kk.x + q.y * kk.y + q.z * kk.z + q.w * kk.w;
    }
    P[i][j] = d * 0.125f;
  }
  __syncthreads();
  if (t < 50) {
    float m = -1e30f;
    for (int j = 0; j < 50; ++j) m = fmaxf(m, P[t][j]);
    float s = 0.f;
    for (int j = 0; j < 50; ++j) { float v = __expf(P[t][j] - m); P[t][j] = v; s += v; }
    float inv = 1.f / s;
    for (int j = 0; j < 50; ++j) P[t][j] *= inv;
  }
  __syncthreads();
  for (int e = t; e < 3200; e += 256) {
    int i = e >> 6, c = e & 63;
    float a = 0.f;
    for (int j = 0; j < 50; ++j) a += P[i][j] * vs[j][c];
    ATT[(size_t)(bl * 50 + i) * 256 + hc + c] = a;
  }
}

// ---------------- fused residual + LayerNorm (wave per row) ----------------
__global__ __launch_bounds__(256) void k_ln_res(
    const float* __restrict__ res, const float* __restrict__ add, int addld,
    float* __restrict__ dst, const float* __restrict__ g, const float* __restrict__ bt)
{
  int row = blockIdx.x * 4 + (threadIdx.x >> 6);
  int lane = threadIdx.x & 63;
  int c = lane * 4;
  float4 rv = *(const float4*)&res[(size_t)row * 256 + c];
  float4 av = *(const float4*)&add[(size_t)row * addld + c];
  float x0 = rv.x + av.x, x1 = rv.y + av.y, x2 = rv.z + av.z, x3 = rv.w + av.w;
  float s = x0 + x1 + x2 + x3;
  float sq = x0 * x0 + x1 * x1 + x2 * x2 + x3 * x3;
#pragma unroll
  for (int d = 1; d < 64; d <<= 1) { s += __shfl_xor(s, d, 64); sq += __shfl_xor(sq, d, 64); }
  float m = s * (1.f / 256.f);
  float var = sq * (1.f / 256.f) - m * m;
  float rs = rsqrtf(var + 1e-5f);
  float4 gv = *(const float4*)&g[c];
  float4 bv = *(const float4*)&bt[c];
  float4 ov;
  ov.x = (x0 - m) * rs * gv.x + bv.x;
  ov.y = (x1 - m) * rs * gv.y + bv.y;
  ov.z = (x2 - m) * rs * gv.z + bv.z;
  ov.w = (x3 - m) * rs * gv.w + bv.w;
  *(float4*)&dst[(size_t)row * 256 + c] = ov;
}

// ---------------- mean over O ----------------
__global__ __launch_bounds__(256) void k_reduce_oenc(const float* __restrict__ H2,
                                                     float* __restrict__ OENC) {
  int b = blockIdx.x, t = threadIdx.x;
  float s = 0.f;
  for (int o = 0; o < 50; ++o) s += H2[((size_t)b * 50 + o) * 256 + t];
  OENC[(size_t)b * 256 + t] = s * 0.02f;
}

// ---------------- temporal encoder + final classifier ----------------
__global__ __launch_bounds__(128) void k_heads(
    const float* __restrict__ daysb, const float* __restrict__ dayss,
    const float* __restrict__ te1_w, const float* __restrict__ te1_b,
    const float* __restrict__ ln1g, const float* __restrict__ ln1b,
    const float* __restrict__ te2_w, const float* __restrict__ te2_b,
    const float* __restrict__ ln2g, const float* __restrict__ ln2b,
    const float* __restrict__ OENC, const float* __restrict__ cWT /*[320][128]*/,
    const float* __restrict__ c_b, const float* __restrict__ clng,
    const float* __restrict__ clnb, float* __restrict__ out)
{
  __shared__ float feat[2];
  __shared__ float s1[32], s2[64], pre[128], stat[2];
  int b = blockIdx.x, t = threadIdx.x;
  if (t == 0) {
    float f0 = 0.f;
    for (int i = 0; i < 10; ++i) f0 += daysb[b * 10 + i];
    feat[0] = f0 * 0.1f;
    feat[1] = dayss[b];
  }
  __syncthreads();
  if (t < 32) s1[t] = te1_b[t] + feat[0] * te1_w[2 * t] + feat[1] * te1_w[2 * t + 1];
  __syncthreads();
  if (t == 0) {
    float s = 0.f; for (int j = 0; j < 32; ++j) s += s1[j];
    float m = s * (1.f / 32.f);
    float v = 0.f; for (int j = 0; j < 32; ++j) { float d = s1[j] - m; v += d * d; }
    stat[0] = m; stat[1] = rsqrtf(v * (1.f / 32.f) + 1e-5f);
  }
  __syncthreads();
  if (t < 32) s1[t] = fmaxf((s1[t] - stat[0]) * stat[1] * ln1g[t] + ln1b[t], 0.f);
  __syncthreads();
  if (t < 64) {
    float a = te2_b[t];
    for (int k = 0; k < 32; ++k) a += s1[k] * te2_w[t * 32 + k];
    s2[t] = a;
  }
  __syncthreads();
  if (t == 0) {
    float s = 0.f; for (int j = 0; j < 64; ++j) s += s2[j];
    float m = s * (1.f / 64.f);
    float v = 0.f; for (int j = 0; j < 64; ++j) { float d = s2[j] - m; v += d * d; }
    stat[0] = m; stat[1] = rsqrtf(v * (1.f / 64.f) + 1e-5f);
  }
  __syncthreads();
  if (t < 64) s2[t] = fmaxf((s2[t] - stat[0]) * stat[1] * ln2g[t] + ln2b[t], 0.f);
  __syncthreads();
  {
    float p = c_b[t];
    const float* oe = OENC + (size_t)b * 256;
    for (int k = 0; k < 256; ++k) p += oe[k] * cWT[k * 128 + t];
    for (int k = 0; k < 64; ++k)  p += s2[k] * cWT[(256 + k) * 128 + t];
    pre[t] = p;
  }
  __syncthreads();
  if (t == 0) {
    float s = 0.f; for (int j = 0; j < 128; ++j) s += pre[j];
    float m = s * (1.f / 128.f);
    float v = 0.f; for (int j = 0; j < 128; ++j) { float d = pre[j] - m; v += d * d; }
    stat[0] = m; stat[1] = rsqrtf(v * (1.f / 128.f) + 1e-5f);
  }
  __syncthreads();
  out[(size_t)b * 128 + t] = fmaxf((pre[t] - stat[0]) * stat[1] * clng[t] + clnb[t], 0.f);
}

// ---------------- host launcher ----------------
extern "C" void kernel_launch(void* const* d_in, const int* in_sizes, int n_in,
                              void* d_out, int out_size, void* d_ws, size_t ws_size,
                              hipStream_t stream)
{
  const int*   oh       = (const int*)d_in[0];
  const float* daysb    = (const float*)d_in[1];
  const float* dayss    = (const float*)d_in[2];
  const float* emb      = (const float*)d_in[3];
  const float* ia_in_w  = (const float*)d_in[4];
  const float* ia_in_b  = (const float*)d_in[5];
  const float* ia_out_w = (const float*)d_in[6];
  const float* ia_out_b = (const float*)d_in[7];
  const float* gf_wi = (const float*)d_in[8];
  const float* gf_wh = (const float*)d_in[9];
  const float* gf_bi = (const float*)d_in[10];
  const float* gf_bh = (const float*)d_in[11];
  const float* gb_wi = (const float*)d_in[12];
  const float* gb_wh = (const float*)d_in[13];
  const float* gb_bi = (const float*)d_in[14];
  const float* gb_bh = (const float*)d_in[15];
  const float* ta_in_w  = (const float*)d_in[16];
  const float* ta_in_b  = (const float*)d_in[17];
  const float* ta_out_w = (const float*)d_in[18];
  const float* ta_out_b = (const float*)d_in[19];
  const float* t_ln1_g = (const float*)d_in[20];
  const float* t_ln1_b = (const float*)d_in[21];
  const float* t_ln2_g = (const float*)d_in[22];
  const float* t_ln2_b = (const float*)d_in[23];
  const float* t_ff1_w = (const float*)d_in[24];
  const float* t_ff1_b = (const float*)d_in[25];
  const float* t_ff2_w = (const float*)d_in[26];
  const float* t_ff2_b = (const float*)d_in[27];
  const float* te1_w = (const float*)d_in[28];
  const float* te1_b = (const float*)d_in[29];
  const float* te_ln1_g = (const float*)d_in[30];
  const float* te_ln1_b = (const float*)d_in[31];
  const float* te2_w = (const float*)d_in[32];
  const float* te2_b = (const float*)d_in[33];
  const float* te_ln2_g = (const float*)d_in[34];
  const float* te_ln2_b = (const float*)d_in[35];
  const float* c_w   = (const float*)d_in[36];
  const float* c_b   = (const float*)d_in[37];
  const float* c_ln_g = (const float*)d_in[38];
  const float* c_ln_b = (const float*)d_in[39];

  float* ws = (float*)d_ws;
  // layout (floats):
  const size_t OFF_G    = 0;                        // [B*O][256] fp32  13,107,200
  const size_t OFF_X    = 13107200;                 // [B*O][64]  fp32   3,276,800
  const size_t OFF_S    = 16384000;                 // scratch slot     12,288,000
  const size_t OFF_OENC = OFF_S + 12288000;         // [B][256]            262,144
  const size_t OW_C     = OFF_OENC + 262144;        // [320][128]           40,960
  const size_t OW_BF    = OW_C + 40960;             // bf16 pool 684,032 ush = 342,016 fl
  const size_t TOTAL    = OW_BF + 342016;           // 29,317,120 fl = 117.3 MB
  if (ws_size < TOTAL * sizeof(float)) return;

  float* Gbuf = ws + OFF_G;
  float* X    = ws + OFF_X;
  float* OENC = ws + OFF_OENC;
  float* w_c  = ws + OW_C;
  unsigned short* bfp = (unsigned short*)(ws + OW_BF);
  unsigned short* b_ta_in  = bfp;                  // 196,608
  unsigned short* b_ta_out = b_ta_in + 196608;     //  65,536
  unsigned short* b_ff1    = b_ta_out + 65536;     // 131,072
  unsigned short* b_ff2    = b_ff1 + 131072;       // 131,072
  unsigned short* b_ia_in  = b_ff2 + 131072;       //  12,288
  unsigned short* b_wi_f   = b_ia_in + 12288;      //  24,576
  unsigned short* b_wi_b   = b_wi_f + 24576;       //  24,576
  unsigned short* b_wh_f   = b_wi_b + 24576;       //  49,152
  unsigned short* b_wh_b   = b_wh_f + 49152;       //  49,152

  // scratch phase views:
  unsigned short* QKVbf = (unsigned short*)(ws + OFF_S);    // item: 24,576,000 ush
  unsigned short* GIf   = (unsigned short*)(ws + OFF_S);    // gru: [GROWS][384] x2
  unsigned short* GIb   = GIf + (size_t)GROWS * 384;
  float* BIG  = ws + OFF_S;                 // transformer: [6400][768]
  float* ATTb = BIG + 4915200;              // [6400][256]
  float* F1   = ATTb + 1638400;             // [6400][512]
  float* O1   = F1;
  float* O2   = F1 + 3276800;               // [6400][256]

  k_transpose<<<(320 * 128 + 255) / 256, 256, 0, stream>>>(c_w, w_c, 128, 320);
  #define CV(SRC, DST, N) k_f32bf16<<<((N)+255)/256, 256, 0, stream>>>(SRC, DST, N)
  CV(ta_in_w,  b_ta_in,  196608);
  CV(ta_out_w, b_ta_out, 65536);
  CV(t_ff1_w,  b_ff1,    131072);
  CV(t_ff2_w,  b_ff2,    131072);
  CV(ia_in_w,  b_ia_in,  12288);
  CV(gf_wi,    b_wi_f,   24576);
  CV(gb_wi,    b_wi_b,   24576);
  CV(gf_wh,    b_wh_f,   49152);
  CV(gb_wh,    b_wh_b,   49152);
  #undef CV

  // ---- item attention: 8 chunks of IP pairs ----
  for (int ci = 0; ci < (B_ * O_) / IP; ++ci) {
    k_gemm_mfma<1, 0, 1><<<dim3(192 / 64, IROWS / 64), 256, 0, stream>>>(
        nullptr, 0, oh + (size_t)ci * IROWS, emb, b_ia_in, 64, ia_in_b,
        nullptr, QKVbf, 192);
    k_item_core<<<IP / 4, 256, 0, stream>>>(QKVbf, ia_out_w, ia_out_b, X + (size_t)ci * IP * 64);
  }

  // ---- bidirectional GRU: 2 chunks of GCHUNK batch rows ----
  for (int gc = 0; gc < B_ / GCHUNK; ++gc) {
    const float* Xc = X + (size_t)gc * GROWS * 64;
    k_gemm_mfma<0, 0, 1><<<dim3(384 / 64, GROWS / 64), 256, 0, stream>>>(
        Xc, 64, nullptr, nullptr, b_wi_f, 64, gf_bi, nullptr, GIf, 384);
    k_gemm_mfma<0, 0, 1><<<dim3(384 / 64, GROWS / 64), 256, 0, stream>>>(
        Xc, 64, nullptr, nullptr, b_wi_b, 64, gb_bi, nullptr, GIb, 384);
    k_gru_mfma<<<256, 512, 0, stream>>>(GIf, GIb, b_wh_f, b_wh_b, gf_bh, gb_bh,
                                        Gbuf + (size_t)gc * GROWS * 256);
  }

  // ---- transformer layer: 8 chunks of CB batch rows ----
  for (int c = 0; c < B_ / CB; ++c) {
    float* Gc = Gbuf + (size_t)c * CROWS * 256;
    k_gemm_mfma<0, 0, 0><<<dim3(768 / 64, CROWS / 64), 256, 0, stream>>>(
        Gc, 256, nullptr, nullptr, b_ta_in, 256, ta_in_b, BIG, nullptr, 768);
    k_attn_core<<<CB * 4, 256, 0, stream>>>(BIG, ATTb);
    k_gemm_mfma<0, 0, 0><<<dim3(256 / 64, CROWS / 64), 256, 0, stream>>>(
        ATTb, 256, nullptr, nullptr, b_ta_out, 256, ta_out_b, O1, nullptr, 256);
    k_ln_res<<<CROWS / 4, 256, 0, stream>>>(Gc, O1, 256, Gc, t_ln1_g, t_ln1_b);
    k_gemm_mfma<0, 1, 0><<<dim3(512 / 64, CROWS / 64), 256, 0, stream>>>(
        Gc, 256, nullptr, nullptr, b_ff1, 256, t_ff1_b, F1, nullptr, 512);
    k_gemm_mfma<0, 0, 0><<<dim3(256 / 64, CROWS / 64), 256, 0, stream>>>(
        F1, 512, nullptr, nullptr, b_ff2, 512, t_ff2_b, O2, nullptr, 256);
    k_ln_res<<<CROWS / 4, 256, 0, stream>>>(Gc, O2, 256, Gc, t_ln2_g, t_ln2_b);
  }

  k_reduce_oenc<<<B_, 256, 0, stream>>>(Gbuf, OENC);
  k_heads<<<B_, 128, 0, stream>>>(daysb, dayss, te1_w, te1_b, te_ln1_g, te_ln1_b,
                                  te2_w, te2_b, te_ln2_g, te_ln2_b,
                                  OENC, w_c, c_b, c_ln_g, c_ln_b, (float*)d_out);
}